// Round 10
// baseline (396.137 us; speedup 1.0000x reference)
//
#include <hip/hip_runtime.h>

#define N_NODES 100000
#define N_EDGES 3200000
#define D 128
#define K 8

// |score32| below this => exact fp64 repair. bf16x3 GEMM score sigma ~2e-5,
// so 4e-3 is ~200 sigma. Bucketed-scatter LDS-order sums also covered.
#define TAU 4e-3f
#define WL_CAP 262144  // repair worklist capacity

#define CHUNK 96   // nodes per head_gemm block (51.5->49.9KB LDS, 3 blocks/CU)
#define GWAVES 8   // waves per head_gemm block (512 threads, 2x4 wave tiling)

// ---- bucketed scatter geometry ----
#define BKT 128                          // dst nodes per bucket
#define NB  ((N_NODES + BKT - 1) / BKT)  // 782 buckets
#define EPB 8192                         // R20: 16384->8192 -> 391 blocks
#define NEB ((N_EDGES + EPB - 1) / EPB)  // 391 blocks (was 196 = 0.76/CU)

typedef float  f32x4  __attribute__((ext_vector_type(4)));
typedef __bf16 bf16x8 __attribute__((ext_vector_type(8)));

static __device__ __forceinline__ unsigned short bfbits(float f)
{
    const __bf16 b = (__bf16)f;           // RNE truncation f32 -> bf16
    return __builtin_bit_cast(unsigned short, b);
}
static __device__ __forceinline__ float bfback(unsigned short u)
{
    return (float)__builtin_bit_cast(__bf16, u);
}

// async global->LDS, 16B per lane. LDS dest = wave-uniform base + lane*16
// (m104); swizzle achieved by pre-swizzling the per-lane GLOBAL source (m173).
static __device__ __forceinline__ void gload_lds16(const void* g, void* l)
{
    __builtin_amdgcn_global_load_lds(
        (const __attribute__((address_space(1))) unsigned int*)g,
        (__attribute__((address_space(3))) unsigned int*)l, 16, 0, 0);
}

// ---------------------------------------------------------------------------
// Phase 0: per-head compaction of masked node ids + per-node mask bitmap.
// ---------------------------------------------------------------------------
__global__ __launch_bounds__(256)
void compact_kernel(const float* __restrict__ mask,
                    int* __restrict__ lists,
                    int* __restrict__ cnts,
                    unsigned char* __restrict__ mb)
{
    __shared__ int wcnt[4][K];
    __shared__ int wbase[4][K];

    const int n = blockIdx.x * 256 + threadIdx.x;
    const int lane = threadIdx.x & 63;
    const int wave = threadIdx.x >> 6;
    const bool valid = (n < N_NODES);

    unsigned long long ball[K];
    int bits8 = 0;
    #pragma unroll
    for (int k = 0; k < K; ++k) {
        const bool m = valid && (mask[(size_t)n * K + k] > 0.0f);
        bits8 |= m ? (1 << k) : 0;
        ball[k] = __ballot(m);
        if (lane == 0) wcnt[wave][k] = __popcll(ball[k]);
    }
    __syncthreads();

    if (threadIdx.x < K) {
        const int k = threadIdx.x;
        const int t0 = wcnt[0][k], t1 = wcnt[1][k], t2 = wcnt[2][k], t3 = wcnt[3][k];
        const int base = (t0 + t1 + t2 + t3)
                       ? atomicAdd(&cnts[k], t0 + t1 + t2 + t3) : 0;
        wbase[0][k] = base;
        wbase[1][k] = base + t0;
        wbase[2][k] = base + t0 + t1;
        wbase[3][k] = base + t0 + t1 + t2;
    }
    __syncthreads();

    #pragma unroll
    for (int k = 0; k < K; ++k) {
        if ((ball[k] >> lane) & 1ull) {
            const int pos = __popcll(ball[k] & ((1ull << lane) - 1ull));
            lists[(size_t)k * N_NODES + wbase[wave][k] + pos] = n;
        }
    }
    if (valid) mb[n] = (unsigned char)bits8;
}

// ---------------------------------------------------------------------------
// Phase 0b: split Ww into bf16 hi/lo, TRANSPOSED to [k][col][kk].
// ---------------------------------------------------------------------------
__global__ __launch_bounds__(256)
void wsplit_kernel(const float* __restrict__ Ww,
                   unsigned short* __restrict__ wtH,
                   unsigned short* __restrict__ wtL)
{
    const int t = blockIdx.x * 256 + threadIdx.x;
    if (t >= K * D * D) return;
    const int k   = t >> 14;       // D*D = 16384
    const int kk  = (t >> 7) & 127;
    const int col = t & 127;
    const float v = Ww[t];
    const __bf16 h = (__bf16)v;
    const __bf16 l = (__bf16)(v - (float)h);
    const int o = (k << 14) | (col << 7) | kk;
    wtH[o] = __builtin_bit_cast(unsigned short, h);
    wtL[o] = __builtin_bit_cast(unsigned short, l);
}

// ---------------------------------------------------------------------------
// Phase 0c (R20): split x into bf16 hi/lo rows ONCE per node (head_gemm was
// re-converting each node ~4.2x across heads and is phase-work-bound, not
// occupancy-bound: R9 occ 37->57% left dur at 94us). Also folds the exact
// fp32 base32 = x.Wm dot (trivial 0.2 GFLOP), deleting redB from head_gemm.
// ---------------------------------------------------------------------------
__global__ __launch_bounds__(256)
void xsplit_kernel(const float* __restrict__ x,
                   const float* __restrict__ Wm,
                   unsigned short* __restrict__ xh,
                   unsigned short* __restrict__ xl,
                   float* __restrict__ b32)
{
    __shared__ float wm[K * D];          // 4 KB
    __shared__ float red[64][4][K];      // 8 KB
    const int tid = threadIdx.x;
    const int n0 = blockIdx.x * 64;
    for (int i = tid; i < K * D; i += 256) wm[i] = Wm[i];
    __syncthreads();

    const int row = tid >> 2;
    const int q   = tid & 3;
    const int n   = n0 + row;
    float bp[K];
    #pragma unroll
    for (int k = 0; k < K; ++k) bp[k] = 0.0f;

    if (n < N_NODES) {
        const float4* xr = (const float4*)(x + (size_t)n * D);
        #pragma unroll
        for (int i = 0; i < 8; ++i) {
            const int f4 = q + 4 * i;    // 4 consecutive lanes = 64B coalesced
            const float4 v = xr[f4];
            ushort4 h, l;
            h.x = bfbits(v.x); l.x = bfbits(v.x - bfback(h.x));
            h.y = bfbits(v.y); l.y = bfbits(v.y - bfback(h.y));
            h.z = bfbits(v.z); l.z = bfbits(v.z - bfback(h.z));
            h.w = bfbits(v.w); l.w = bfbits(v.w - bfback(h.w));
            *(ushort4*)(xh + (size_t)n * D + f4 * 4) = h;
            *(ushort4*)(xl + (size_t)n * D + f4 * 4) = l;
            const int j0 = f4 * 4;
            #pragma unroll
            for (int k = 0; k < K; ++k)
                bp[k] += v.x * wm[k * D + j0]     + v.y * wm[k * D + j0 + 1]
                       + v.z * wm[k * D + j0 + 2] + v.w * wm[k * D + j0 + 3];
        }
    }
    #pragma unroll
    for (int k = 0; k < K; ++k) red[row][q][k] = bp[k];
    __syncthreads();

    for (int t = tid; t < 64 * K; t += 256) {
        const int rr = t >> 3;
        const int k  = t & 7;
        const int nn = n0 + rr;
        if (nn < N_NODES)
            b32[(size_t)nn * K + k] = red[rr][0][k] + red[rr][1][k]
                                    + red[rr][2][k] + red[rr][3][k];
    }
}

// ---------------------------------------------------------------------------
// Phase 1 (bf16x3 MFMA, list version, R20): staging = 6 async
// global_load_lds per wave (zero staging VALU). Swizzle preserved by
// pre-swizzled source: LDS row r bytes [v,v+16) hold xh_row[v ^ ((r&7)<<4)]
// -- identical layout to the old in-kernel staging, MFMA loop unchanged.
// ---------------------------------------------------------------------------
__global__ __launch_bounds__(512, 4)
void head_gemm_kernel(const unsigned short* __restrict__ xh,
                      const unsigned short* __restrict__ xl,
                      const unsigned short* __restrict__ wtH,
                      const unsigned short* __restrict__ wtL,
                      const float* __restrict__ Wm,
                      const int* __restrict__ lists,
                      const int* __restrict__ cnts,
                      float* __restrict__ t32)
{
    __shared__ __align__(16) unsigned short Ah[CHUNK * D];  // 24 KB
    __shared__ __align__(16) unsigned short Al[CHUNK * D];  // 24 KB
    __shared__ float redT[GWAVES][48];                      // 1.5 KB
    __shared__ int   ids[CHUNK];                            // 384 B

    const int bid = blockIdx.x;
    const int k = (bid >> 3) & 7;
    const int c = ((bid >> 6) << 3) | (bid & 7);   // XCD swizzle

    const int cnt = cnts[k];
    const int nbase = c * CHUNK;
    if (nbase >= cnt) return;            // block-uniform exit (before barriers)

    const int tid = threadIdx.x;
    const int lane = tid & 63;
    const int wave = __builtin_amdgcn_readfirstlane((int)(tid >> 6));
    const int* list = lists + (size_t)k * N_NODES;

    if (tid < CHUNK) {
        int idx = nbase + tid;
        if (idx >= cnt) idx = cnt - 1;   // tail rows duplicated, writes guarded
        ids[tid] = list[idx];
    }
    __syncthreads();

    // ---- async staging: wave w fills rows [12w, 12w+12) of Ah and Al ----
    {
        #pragma unroll
        for (int j = 0; j < 3; ++j) {
            const int R = wave * 12 + j * 4;      // wave-uniform
            const int r = R + (lane >> 4);        // this lane's row
            const int id = ids[r];
            const int so = (((lane & 15) ^ (r & 7)) << 4);   // src byte offset
            gload_lds16((const char*)(xh + (size_t)id * D) + so,
                        (char*)Ah + R * 256);
            gload_lds16((const char*)(xl + (size_t)id * D) + so,
                        (char*)Al + R * 256);
        }
    }
    __syncthreads();                     // vmcnt(0) drained by compiler

    // ---- MFMA main loop (no barriers) ----
    const int wm_ = wave >> 2;           // wave_m: rows wm_*48 .. +47
    const int wn  = wave & 3;            // wave_n: cols wn*32 .. +31
    const int l15 = lane & 15;
    const int lg  = lane >> 4;
    const int n0  = wn * 32;

    f32x4 acc[3][2];
    #pragma unroll
    for (int mf = 0; mf < 3; ++mf) {
        acc[mf][0] = (f32x4){0.f, 0.f, 0.f, 0.f};
        acc[mf][1] = (f32x4){0.f, 0.f, 0.f, 0.f};
    }

    const unsigned short* bH0 = wtH + (((k * D + n0 + l15) << 7) + 8 * lg);
    const unsigned short* bH1 = bH0 + (16 << 7);
    const unsigned short* bL0 = wtL + (((k * D + n0 + l15) << 7) + 8 * lg);
    const unsigned short* bL1 = bL0 + (16 << 7);

    #pragma unroll
    for (int s = 0; s < 4; ++s) {
        const int ko = s * 32;
        const bf16x8 Bh0 = *reinterpret_cast<const bf16x8*>(bH0 + ko);
        const bf16x8 Bh1 = *reinterpret_cast<const bf16x8*>(bH1 + ko);
        const bf16x8 Bl0 = *reinterpret_cast<const bf16x8*>(bL0 + ko);
        const bf16x8 Bl1 = *reinterpret_cast<const bf16x8*>(bL1 + ko);
        #pragma unroll
        for (int mf = 0; mf < 3; ++mf) {
            const int m = wm_ * 48 + mf * 16 + l15;
            const int byt = (m * 256 + (ko + 8 * lg) * 2) ^ ((m & 7) << 4);
            const bf16x8 Amh = *reinterpret_cast<const bf16x8*>(&Ah[byt >> 1]);
            const bf16x8 Aml = *reinterpret_cast<const bf16x8*>(&Al[byt >> 1]);
            acc[mf][0] = __builtin_amdgcn_mfma_f32_16x16x32_bf16(Amh, Bh0, acc[mf][0], 0, 0, 0);
            acc[mf][1] = __builtin_amdgcn_mfma_f32_16x16x32_bf16(Amh, Bh1, acc[mf][1], 0, 0, 0);
            acc[mf][0] = __builtin_amdgcn_mfma_f32_16x16x32_bf16(Amh, Bl0, acc[mf][0], 0, 0, 0);
            acc[mf][1] = __builtin_amdgcn_mfma_f32_16x16x32_bf16(Amh, Bl1, acc[mf][1], 0, 0, 0);
            acc[mf][0] = __builtin_amdgcn_mfma_f32_16x16x32_bf16(Aml, Bh0, acc[mf][0], 0, 0, 0);
            acc[mf][1] = __builtin_amdgcn_mfma_f32_16x16x32_bf16(Aml, Bh1, acc[mf][1], 0, 0, 0);
        }
    }

    // ---- epilogue: relu, dot with Wm over this wave's 32 cols, reduce ----
    const float wmv0 = Wm[k * D + n0 + l15];
    const float wmv1 = Wm[k * D + n0 + 16 + l15];
    float keep = 0.0f;
    #pragma unroll
    for (int mf = 0; mf < 3; ++mf) {
        #pragma unroll
        for (int r = 0; r < 4; ++r) {
            float p = fmaxf(acc[mf][0][r], 0.0f) * wmv0
                    + fmaxf(acc[mf][1][r], 0.0f) * wmv1;
            p += __shfl_xor(p, 1);
            p += __shfl_xor(p, 2);
            p += __shfl_xor(p, 4);
            p += __shfl_xor(p, 8);       // all 16 lanes of group lg hold sum
            if (l15 == mf * 4 + r) keep = p;
        }
    }
    if (l15 < 12)
        redT[wave][((l15 >> 2) << 4) + (lg << 2) + (l15 & 3)] = keep;
    __syncthreads();

    if (tid < CHUNK) {
        const int r = tid;
        const int idx = nbase + r;
        if (idx < cnt) {
            const int wg = r / 48;
            const int rl = r - wg * 48;
            const float ts = redT[wg * 4 + 0][rl] + redT[wg * 4 + 1][rl]
                           + redT[wg * 4 + 2][rl] + redT[wg * 4 + 3][rl];
            t32[(size_t)ids[r] * K + k] = ts;
        }
    }
}

// ---------------------------------------------------------------------------
// Phase 1 fallback (R9-proven, computes base32 itself): used when ws_size is
// too small for xh/xl.
// ---------------------------------------------------------------------------
__global__ __launch_bounds__(512, 4)
void head_gemm_f32_kernel(const float* __restrict__ x,
                          const unsigned short* __restrict__ wtH,
                          const unsigned short* __restrict__ wtL,
                          const float* __restrict__ Wm,
                          const int* __restrict__ lists,
                          const int* __restrict__ cnts,
                          float* __restrict__ t32,
                          float* __restrict__ base32)
{
    __shared__ __align__(16) unsigned short Ah[CHUNK * D];
    __shared__ __align__(16) unsigned short Al[CHUNK * D];
    __shared__ float redT[GWAVES][48];
    __shared__ float redB[CHUNK][4];
    __shared__ int   ids[CHUNK];

    const int bid = blockIdx.x;
    const int k = (bid >> 3) & 7;
    const int c = ((bid >> 6) << 3) | (bid & 7);

    const int cnt = cnts[k];
    const int nbase = c * CHUNK;
    if (nbase >= cnt) return;

    const int tid = threadIdx.x;
    const int lane = tid & 63;
    const int wave = __builtin_amdgcn_readfirstlane((int)(tid >> 6));
    const int* list = lists + (size_t)k * N_NODES;

    if (tid < CHUNK) {
        int idx = nbase + tid;
        if (idx >= cnt) idx = cnt - 1;
        ids[tid] = list[idx];
    }
    __syncthreads();

    if (tid < CHUNK * 4) {
        const int r = tid >> 2;
        const int q = tid & 3;
        const int id = ids[r];
        const float4* xr  = (const float4*)(x + (size_t)id * D);
        const float4* wm4 = (const float4*)(Wm + k * D);
        float bp = 0.0f;
        #pragma unroll
        for (int i = 0; i < 8; ++i) {
            const int f4 = q + 4 * i;
            const float4 v  = xr[f4];
            const float4 wv = wm4[f4];
            bp += v.x * wv.x + v.y * wv.y + v.z * wv.z + v.w * wv.w;
            ushort4 h, l;
            h.x = bfbits(v.x); l.x = bfbits(v.x - bfback(h.x));
            h.y = bfbits(v.y); l.y = bfbits(v.y - bfback(h.y));
            h.z = bfbits(v.z); l.z = bfbits(v.z - bfback(h.z));
            h.w = bfbits(v.w); l.w = bfbits(v.w - bfback(h.w));
            const int boff = ((r * 256 + f4 * 8) ^ ((r & 7) << 4)) >> 1;
            *(ushort4*)&Ah[boff] = h;
            *(ushort4*)&Al[boff] = l;
        }
        redB[r][q] = bp;
    }
    __syncthreads();

    const int wm_ = wave >> 2;
    const int wn  = wave & 3;
    const int l15 = lane & 15;
    const int lg  = lane >> 4;
    const int n0  = wn * 32;

    f32x4 acc[3][2];
    #pragma unroll
    for (int mf = 0; mf < 3; ++mf) {
        acc[mf][0] = (f32x4){0.f, 0.f, 0.f, 0.f};
        acc[mf][1] = (f32x4){0.f, 0.f, 0.f, 0.f};
    }

    const unsigned short* bH0 = wtH + (((k * D + n0 + l15) << 7) + 8 * lg);
    const unsigned short* bH1 = bH0 + (16 << 7);
    const unsigned short* bL0 = wtL + (((k * D + n0 + l15) << 7) + 8 * lg);
    const unsigned short* bL1 = bL0 + (16 << 7);

    #pragma unroll
    for (int s = 0; s < 4; ++s) {
        const int ko = s * 32;
        const bf16x8 Bh0 = *reinterpret_cast<const bf16x8*>(bH0 + ko);
        const bf16x8 Bh1 = *reinterpret_cast<const bf16x8*>(bH1 + ko);
        const bf16x8 Bl0 = *reinterpret_cast<const bf16x8*>(bL0 + ko);
        const bf16x8 Bl1 = *reinterpret_cast<const bf16x8*>(bL1 + ko);
        #pragma unroll
        for (int mf = 0; mf < 3; ++mf) {
            const int m = wm_ * 48 + mf * 16 + l15;
            const int byt = (m * 256 + (ko + 8 * lg) * 2) ^ ((m & 7) << 4);
            const bf16x8 Amh = *reinterpret_cast<const bf16x8*>(&Ah[byt >> 1]);
            const bf16x8 Aml = *reinterpret_cast<const bf16x8*>(&Al[byt >> 1]);
            acc[mf][0] = __builtin_amdgcn_mfma_f32_16x16x32_bf16(Amh, Bh0, acc[mf][0], 0, 0, 0);
            acc[mf][1] = __builtin_amdgcn_mfma_f32_16x16x32_bf16(Amh, Bh1, acc[mf][1], 0, 0, 0);
            acc[mf][0] = __builtin_amdgcn_mfma_f32_16x16x32_bf16(Amh, Bl0, acc[mf][0], 0, 0, 0);
            acc[mf][1] = __builtin_amdgcn_mfma_f32_16x16x32_bf16(Amh, Bl1, acc[mf][1], 0, 0, 0);
            acc[mf][0] = __builtin_amdgcn_mfma_f32_16x16x32_bf16(Aml, Bh0, acc[mf][0], 0, 0, 0);
            acc[mf][1] = __builtin_amdgcn_mfma_f32_16x16x32_bf16(Aml, Bh1, acc[mf][1], 0, 0, 0);
        }
    }

    const float wmv0 = Wm[k * D + n0 + l15];
    const float wmv1 = Wm[k * D + n0 + 16 + l15];
    float keep = 0.0f;
    #pragma unroll
    for (int mf = 0; mf < 3; ++mf) {
        #pragma unroll
        for (int r = 0; r < 4; ++r) {
            float p = fmaxf(acc[mf][0][r], 0.0f) * wmv0
                    + fmaxf(acc[mf][1][r], 0.0f) * wmv1;
            p += __shfl_xor(p, 1);
            p += __shfl_xor(p, 2);
            p += __shfl_xor(p, 4);
            p += __shfl_xor(p, 8);
            if (l15 == mf * 4 + r) keep = p;
        }
    }
    if (l15 < 12)
        redT[wave][((l15 >> 2) << 4) + (lg << 2) + (l15 & 3)] = keep;
    __syncthreads();

    if (tid < CHUNK) {
        const int r = tid;
        const int idx = nbase + r;
        if (idx < cnt) {
            const int wg = r / 48;
            const int rl = r - wg * 48;
            const float ts = redT[wg * 4 + 0][rl] + redT[wg * 4 + 1][rl]
                           + redT[wg * 4 + 2][rl] + redT[wg * 4 + 3][rl];
            const float bs = redB[r][0] + redB[r][1] + redB[r][2] + redB[r][3];
            const int id = ids[r];
            t32[(size_t)id * K + k]    = ts;
            base32[(size_t)id * K + k] = bs;
        }
    }
}

// ---------------------------------------------------------------------------
// Phase 2 (bucketed scatter + fused combine/flag/worklist). See R13-R19.
// ---------------------------------------------------------------------------
__global__ __launch_bounds__(512)
void ehist_kernel(const int* __restrict__ ei, int* __restrict__ bhist)
{
    __shared__ int lh[NB];
    const int tid = threadIdx.x;
    for (int i = tid; i < NB; i += 512) lh[i] = 0;
    __syncthreads();
    const int e0 = blockIdx.x * EPB;
    #pragma unroll 4
    for (int i = 0; i < EPB / 512; ++i) {
        const int e = e0 + i * 512 + tid;
        if (e < N_EDGES) {
            const int d = ei[(long long)N_EDGES + e];
            atomicAdd(&lh[d >> 7], 1);
        }
    }
    __syncthreads();
    for (int i = tid; i < NB; i += 512) {
        const int c = lh[i];
        if (c) atomicAdd(&bhist[i], c);
    }
}

__global__ __launch_bounds__(1024)
void escan_kernel(const int* __restrict__ bhist,
                  int* __restrict__ bases,
                  int* __restrict__ cursors)
{
    __shared__ int sc[1024];
    const int tid = threadIdx.x;
    const int v = (tid < NB) ? bhist[tid] : 0;
    sc[tid] = v;
    __syncthreads();
    for (int off = 1; off < 1024; off <<= 1) {
        int t = 0;
        if (tid >= off) t = sc[tid - off];
        __syncthreads();
        sc[tid] += t;
        __syncthreads();
    }
    if (tid < NB) {
        const int ex = sc[tid] - v;     // exclusive
        bases[tid]   = ex;
        cursors[tid] = ex;
        if (tid == NB - 1) bases[NB] = sc[tid];
    }
}

__global__ __launch_bounds__(512)
void ebucket_kernel(const int* __restrict__ ei,
                    int* __restrict__ cursors,
                    int* __restrict__ bkt)
{
    __shared__ int lh[NB];
    __shared__ int wb[NB];
    const int tid = threadIdx.x;
    for (int i = tid; i < NB; i += 512) lh[i] = 0;
    __syncthreads();
    const int e0 = blockIdx.x * EPB;
    // pass 1: local counts
    #pragma unroll 4
    for (int i = 0; i < EPB / 512; ++i) {
        const int e = e0 + i * 512 + tid;
        if (e < N_EDGES) atomicAdd(&lh[ei[(long long)N_EDGES + e] >> 7], 1);
    }
    __syncthreads();
    for (int i = tid; i < NB; i += 512) {
        const int c = lh[i];
        wb[i] = c ? atomicAdd(&cursors[i], c) : 0;
        lh[i] = 0;
    }
    __syncthreads();
    // pass 2: rank + write packed records (runs are contiguous -> L2 absorbs)
    #pragma unroll 4
    for (int i = 0; i < EPB / 512; ++i) {
        const int e = e0 + i * 512 + tid;
        if (e < N_EDGES) {
            const int d = ei[(long long)N_EDGES + e];
            const int s = ei[e];
            const int b = d >> 7;
            const int r = atomicAdd(&lh[b], 1);
            const int idx = wb[b] + r;
            if (idx < N_EDGES)           // defensive clamp (always true)
                bkt[idx] = (s << 7) | (d & 127);
        }
    }
}

__global__ __launch_bounds__(512)
void eaccum_kernel(const int* __restrict__ bkt,
                   const int* __restrict__ bases,
                   const unsigned char* __restrict__ mb,
                   const float* __restrict__ t32,
                   const float* __restrict__ base32,
                   float* __restrict__ agg32,
                   float* __restrict__ out,
                   unsigned char* __restrict__ flag8,
                   double* __restrict__ s64,
                   int2* __restrict__ wl,
                   int* __restrict__ wlcnt)
{
    __shared__ float acc[BKT * K];          // 4 KB
    __shared__ unsigned char mbl[BKT];
    __shared__ unsigned char fll[BKT];
    __shared__ int anyfl;
    const int b = blockIdx.x;
    const int n0 = b << 7;
    const int tid = threadIdx.x;
    for (int i = tid; i < BKT * K; i += 512) acc[i] = 0.0f;
    if (tid < BKT) {
        const int n = n0 + tid;
        mbl[tid] = (n < N_NODES) ? mb[n] : 0;
    }
    if (tid == 0) anyfl = 0;
    __syncthreads();

    // ---- accumulate (gate = dst mask only; t32 zero-defined elsewhere) ----
    const int eB = bases[b];
    int eE = bases[b + 1];
    if (eE > N_EDGES) eE = N_EDGES;      // defensive clamp (always no-op)
    for (int e = eB + tid; e < eE; e += 512) {
        const int rec = bkt[e];
        const int s  = rec >> 7;
        const int dl = rec & 127;
        const unsigned md = mbl[dl];
        if (md) {
            const float4* tr = (const float4*)(t32 + (size_t)s * K);
            const float4 t0 = tr[0], t1 = tr[1];
            #pragma unroll
            for (int k = 0; k < K; ++k) {
                const float tv = (k < 4)
                    ? ((k < 2) ? (k == 0 ? t0.x : t0.y) : (k == 2 ? t0.z : t0.w))
                    : ((k < 6) ? (k == 4 ? t1.x : t1.y) : (k == 6 ? t1.z : t1.w));
                if (((md >> k) & 1) && tv != 0.0f)
                    atomicAdd(&acc[(dl << 3) + k], tv);   // ds_add_f32
            }
        }
    }
    __syncthreads();

    // ---- combine + flag for this block's 128 nodes ----
    if (tid < BKT) {
        const int n = n0 + tid;
        if (n < N_NODES) {
            const unsigned m8 = mbl[tid];
            const float4* b4 = (const float4*)(base32 + (size_t)n * K);
            const float4 b40 = b4[0], b41 = b4[1];
            float bs[K];
            bs[0] = b40.x; bs[1] = b40.y; bs[2] = b40.z; bs[3] = b40.w;
            bs[4] = b41.x; bs[5] = b41.y; bs[6] = b41.z; bs[7] = b41.w;
            float o[K];
            int cnt = 0, fl = 0;
            #pragma unroll
            for (int k = 0; k < K; ++k) {
                const float sc = bs[k] + acc[(tid << 3) + k];
                const bool masked = (m8 >> k) & 1;
                const bool hm = masked && (sc > 0.0f);
                if (masked && fabsf(sc) < TAU) fl |= (1 << k);
                o[k] = (hm && cnt < 2) ? 1.0f : 0.0f;
                cnt += hm ? 1 : 0;
            }
            float4* op = (float4*)(out + (size_t)n * K);
            op[0] = make_float4(o[0], o[1], o[2], o[3]);
            op[1] = make_float4(o[4], o[5], o[6], o[7]);
            float4* ap = (float4*)(agg32 + (size_t)n * K);
            ap[0] = make_float4(acc[(tid << 3) + 0], acc[(tid << 3) + 1],
                                acc[(tid << 3) + 2], acc[(tid << 3) + 3]);
            ap[1] = make_float4(acc[(tid << 3) + 4], acc[(tid << 3) + 5],
                                acc[(tid << 3) + 6], acc[(tid << 3) + 7]);
            flag8[n] = (unsigned char)fl;
            fll[tid] = (unsigned char)fl;
            if (fl) {
                anyfl = 1;               // benign race, all write 1
                #pragma unroll
                for (int k = 0; k < K; ++k)
                    if ((fl >> k) & 1) s64[(size_t)n * K + k] = 0.0;
            }
        } else {
            fll[tid] = 0;
        }
    }
    __syncthreads();

    // ---- worklist: rescan OWN records (L2-hot), LDS flag check ----
    if (anyfl) {
        for (int e = eB + tid; e < eE; e += 512) {
            const int rec = bkt[e];
            const int dl = rec & 127;
            unsigned f = fll[dl];
            if (!f) continue;
            const int s = rec >> 7;
            f &= mb[s];                  // rare path: src mask gather ok
            while (f) {
                const int k = __ffs(f) - 1;
                f &= f - 1;
                const int idx = atomicAdd(wlcnt, 1);
                if (idx < WL_CAP) wl[idx] = make_int2(s | (k << 20), n0 + dl);
            }
        }
    }
}

// ---------------------------------------------------------------------------
// Fallback path kernels (used only if ws_size too small for bkt array).
// ---------------------------------------------------------------------------
__global__ __launch_bounds__(256)
void scatter_fallback_kernel(const int* __restrict__ ei,
                             const unsigned char* __restrict__ mb,
                             const float* __restrict__ t32,
                             float* __restrict__ agg32)
{
    const long long tid = (long long)blockIdx.x * 256 + threadIdx.x;
    if (tid >= (long long)N_EDGES * K) return;
    const int k = (int)(tid & (K - 1));
    const long long e = tid >> 3;
    const int d = ei[(long long)N_EDGES + e];
    const int s = ei[e];
    const unsigned md = mb[d] & mb[s];
    if (!((md >> k) & 1)) return;
    const float v = t32[(size_t)s * K + k];
    if (v != 0.0f) atomicAdd(&agg32[(size_t)d * K + k], v);
}

__global__ __launch_bounds__(256)
void combine_flag_kernel(const unsigned char* __restrict__ mb,
                         const float* __restrict__ base32,
                         const float* __restrict__ agg32,
                         float* __restrict__ out,
                         unsigned char* __restrict__ flag8,
                         double* __restrict__ s64)
{
    const int n = blockIdx.x * 256 + threadIdx.x;
    if (n >= N_NODES) return;
    const unsigned m8 = mb[n];
    float o[K];
    int cnt = 0, fl = 0;
    #pragma unroll
    for (int k = 0; k < K; ++k) {
        const float s = base32[(size_t)n * K + k] + agg32[(size_t)n * K + k];
        const bool masked = (m8 >> k) & 1;
        const bool hm = masked && (s > 0.0f);
        if (masked && fabsf(s) < TAU) fl |= (1 << k);
        o[k] = (hm && cnt < 2) ? 1.0f : 0.0f;
        cnt += hm ? 1 : 0;
    }
    float4* op = (float4*)(out + (size_t)n * K);
    op[0] = make_float4(o[0], o[1], o[2], o[3]);
    op[1] = make_float4(o[4], o[5], o[6], o[7]);
    flag8[n] = (unsigned char)fl;
    if (fl) {
        #pragma unroll
        for (int k = 0; k < K; ++k)
            if ((fl >> k) & 1) s64[(size_t)n * K + k] = 0.0;
    }
}

__global__ __launch_bounds__(256)
void edge_flag_kernel(const int* __restrict__ ei,
                      const unsigned char* __restrict__ mb,
                      const unsigned char* __restrict__ flag8,
                      int2* __restrict__ wl,
                      int* __restrict__ wlcnt)
{
    const int e = blockIdx.x * 256 + threadIdx.x;
    if (e >= N_EDGES) return;
    const int d = ei[(long long)N_EDGES + e];
    unsigned f = flag8[d];
    if (!f) return;
    const int s = ei[e];
    f &= mb[s];
    while (f) {
        const int k = __ffs(f) - 1;
        f &= f - 1;
        const int idx = atomicAdd(wlcnt, 1);
        if (idx < WL_CAP) wl[idx] = make_int2(s | (k << 20), d);
    }
}

// ---------------------------------------------------------------------------
// Repair B: one wave per worklist entry: exact fp64 t, atomic into score64.
// ---------------------------------------------------------------------------
__global__ __launch_bounds__(256)
void repair_t_kernel(const float* __restrict__ x,
                     const float* __restrict__ Ww,
                     const float* __restrict__ Wm,
                     const int2* __restrict__ wl,
                     const int* __restrict__ wlcnt,
                     double* __restrict__ score64)
{
    const int lane = threadIdx.x & 63;
    const int waveId = blockIdx.x * 4 + (threadIdx.x >> 6);
    const int nWaves = gridDim.x * 4;
    int cnt = *wlcnt;
    if (cnt > WL_CAP) cnt = WL_CAP;
    for (int w = waveId; w < cnt; w += nWaves) {
        const int2 ent = wl[w];
        const int s = __builtin_amdgcn_readfirstlane(ent.x & 0xFFFFF);
        const int k = __builtin_amdgcn_readfirstlane(ent.x >> 20);
        const int d = ent.y;
        const float* xr = x + (size_t)s * D;
        const float* Wk = Ww + (size_t)k * D * D;
        double c0 = 0.0, c1 = 0.0;
        for (int j = 0; j < D; ++j) {
            const double xd = (double)xr[j];
            c0 = fma(xd, (double)Wk[j * D + lane], c0);
            c1 = fma(xd, (double)Wk[j * D + lane + 64], c1);
        }
        double ts = fmax(c0, 0.0) * (double)Wm[k * D + lane]
                  + fmax(c1, 0.0) * (double)Wm[k * D + lane + 64];
        #pragma unroll
        for (int off = 32; off > 0; off >>= 1) ts += __shfl_xor(ts, off);
        if (lane == 0) atomicAdd(&score64[(size_t)d * K + k], ts);
    }
}

// ---------------------------------------------------------------------------
// Repair C: rewrite output rows of flagged nodes using exact scores.
// ---------------------------------------------------------------------------
__global__ __launch_bounds__(256)
void repair_combine_kernel(const float* __restrict__ x,
                           const unsigned char* __restrict__ mb,
                           const float* __restrict__ Wm,
                           const float* __restrict__ base32,
                           const float* __restrict__ agg32,
                           const double* __restrict__ score64,
                           const unsigned char* __restrict__ flag8,
                           float* __restrict__ out)
{
    const int n = blockIdx.x * 256 + threadIdx.x;
    if (n >= N_NODES) return;
    const unsigned f = flag8[n];
    if (!f) return;
    const unsigned m8 = mb[n];
    float o[K];
    int cnt = 0;
    #pragma unroll
    for (int k = 0; k < K; ++k) {
        bool hm;
        if ((f >> k) & 1) {
            double b = 0.0;
            for (int j = 0; j < D; ++j)
                b = fma((double)x[(size_t)n * D + j], (double)Wm[k * D + j], b);
            hm = (b + score64[(size_t)n * K + k]) > 0.0;
        } else {
            hm = ((m8 >> k) & 1) &&
                 ((base32[(size_t)n * K + k] + agg32[(size_t)n * K + k]) > 0.0f);
        }
        o[k] = (hm && cnt < 2) ? 1.0f : 0.0f;
        cnt += hm ? 1 : 0;
    }
    float4* op = (float4*)(out + (size_t)n * K);
    op[0] = make_float4(o[0], o[1], o[2], o[3]);
    op[1] = make_float4(o[4], o[5], o[6], o[7]);
}

extern "C" void kernel_launch(void* const* d_in, const int* in_sizes, int n_in,
                              void* d_out, int out_size, void* d_ws, size_t ws_size,
                              hipStream_t stream)
{
    const float* x    = (const float*)d_in[0];
    const int*   ei   = (const int*)d_in[1];   // edge_index [2, E] int32
    const float* mask = (const float*)d_in[2]; // [N, K]
    const float* Ww   = (const float*)d_in[3]; // [K, D, D]
    const float* Wm   = (const float*)d_in[4]; // [K, D, 1]
    float* out = (float*)d_out;                // [N, K] float32

    // workspace layout:
    //   [0, 3.2M)            t32      f32[N*K]   (memset 0; head_gemm fills masked)
    //   [3.2M, 6.4M)         agg32    f32[N*K]
    //   [6.4M, 12.8M)        s64      f64[N*K]  (live only from eaccum on)
    //     overlay [6.4M, 9.6M)    lists  int[K][N]          (dead after head_gemm)
    //     overlay [9.6M, 10.13M)  wtH/wtL bf16[K][D][D] x2  (dead after head_gemm)
    //   [12.8M, +100000)     flag8    u8[N]
    //   [12,900,000, +32)    cnts     int[8]
    //   [12,900,032, +4)     wlcnt    int
    //   [12,900,064, +3128)  bhist    int[NB]
    //   [12,903,200, +3132)  bases    int[NB+1]
    //   [12,906,336, +3128)  cursors  int[NB]
    //   [12,909,504, +2M)    wl       int2[WL_CAP]         (ends 15,006,656)
    //   [15,006,656, +3.2M)  b32      f32[N*K]             (ends 18,206,656)
    //   [18,206,656, +100000) mb      u8[N]                (ends 18,306,656)
    //   [18,306,656, +12.8M) bkt      int[N_EDGES]         (ends 31,106,656)
    //   [31,106,688, +25.6M) xh       bf16[N][D]           (ends 56,706,688)
    //   [56,706,688, +25.6M) xl       bf16[N][D]           (ends 82,306,688)
    char* w = (char*)d_ws;
    float*          t32    = (float*)w;
    float*          agg32  = (float*)(w + 3200000);
    double*         s64    = (double*)(w + 6400000);
    int*            lists  = (int*)(w + 6400000);
    unsigned short* wtH    = (unsigned short*)(w + 9600000);
    unsigned short* wtL    = (unsigned short*)(w + 9600000 + 262144);
    unsigned char*  flag8  = (unsigned char*)(w + 12800000);
    int*            cnts   = (int*)(w + 12900000);
    int*            wlcnt  = (int*)(w + 12900032);
    int*            bhist  = (int*)(w + 12900064);
    int*            bases  = (int*)(w + 12903200);
    int*            cursors= (int*)(w + 12906336);
    int2*           wl     = (int2*)(w + 12909504);
    float*          b32    = (float*)(w + 15006656);
    unsigned char*  mb     = (unsigned char*)(w + 18206656);
    int*            bkt    = (int*)(w + 18306656);
    unsigned short* xh     = (unsigned short*)(w + 31106688);
    unsigned short* xl     = (unsigned short*)(w + 56706688);
    const size_t WS_BUCKETED = 31106656;
    const size_t WS_XSPLIT   = 82306688;
    const bool bucketed = (ws_size >= WS_BUCKETED);
    const bool xsplit   = (ws_size >= WS_XSPLIT);

    // zero t32 (defines unmasked entries -> eaccum needs no mb[src] gather)
    hipMemsetAsync(t32, 0, 3200000, stream);
    // zero cnts + wlcnt + bhist (bases/cursors fully written by escan)
    hipMemsetAsync(w + 12900000, 0, 4096, stream);

    wsplit_kernel<<<(K * D * D + 255) / 256, 256, 0, stream>>>(Ww, wtH, wtL);

    compact_kernel<<<(N_NODES + 255) / 256, 256, 0, stream>>>(mask, lists, cnts, mb);

    const int nchunks = (N_NODES + CHUNK - 1) / CHUNK;           // 1042
    const int nc8 = (nchunks + 7) & ~7;                           // 1048
    if (xsplit) {
        xsplit_kernel<<<(N_NODES + 63) / 64, 256, 0, stream>>>(x, Wm, xh, xl, b32);
        head_gemm_kernel<<<nc8 * K, 512, 0, stream>>>(xh, xl, wtH, wtL, Wm,
                                                      lists, cnts, t32);
    } else {
        head_gemm_f32_kernel<<<nc8 * K, 512, 0, stream>>>(x, wtH, wtL, Wm,
                                                          lists, cnts, t32, b32);
    }

    if (bucketed) {
        ehist_kernel<<<NEB, 512, 0, stream>>>(ei, bhist);
        escan_kernel<<<1, 1024, 0, stream>>>(bhist, bases, cursors);
        ebucket_kernel<<<NEB, 512, 0, stream>>>(ei, cursors, bkt);
        eaccum_kernel<<<NB, 512, 0, stream>>>(bkt, bases, mb, t32, b32,
                                              agg32, out, flag8, s64, wl, wlcnt);
    } else {
        hipMemsetAsync(agg32, 0, 3200000, stream);
        const long long nek = (long long)N_EDGES * K;
        scatter_fallback_kernel<<<(int)((nek + 255) / 256), 256, 0, stream>>>(
            ei, mb, t32, agg32);
        combine_flag_kernel<<<(N_NODES + 255) / 256, 256, 0, stream>>>(
            mb, b32, agg32, out, flag8, s64);
        edge_flag_kernel<<<(N_EDGES + 255) / 256, 256, 0, stream>>>(
            ei, mb, flag8, wl, wlcnt);
    }

    repair_t_kernel<<<512, 256, 0, stream>>>(x, Ww, Wm, wl, wlcnt, s64);

    repair_combine_kernel<<<(N_NODES + 255) / 256, 256, 0, stream>>>(
        x, mb, Wm, b32, agg32, s64, flag8, out);
}

// Round 11
// 359.099 us; speedup vs baseline: 1.1031x; 1.1031x over previous
//
#include <hip/hip_runtime.h>

#define N_NODES 100000
#define N_EDGES 3200000
#define D 128
#define K 8

// |score32| below this => exact fp64 repair. bf16x3 GEMM score sigma ~2e-5,
// so 4e-3 is ~200 sigma. Bucketed-scatter LDS-order sums also covered.
#define TAU 4e-3f
#define WL_CAP 262144  // repair worklist capacity

#define CHUNK 96   // nodes per head_gemm block (52.6KB LDS -> 3 blocks/CU)
#define GWAVES 8   // waves per head_gemm block (512 threads, 2x4 wave tiling)

// ---- bucketed scatter geometry (R9-proven) ----
#define BKT 128                          // dst nodes per bucket
#define NB  ((N_NODES + BKT - 1) / BKT)  // 782 buckets
#define EPB 16384                        // edges per hist/bucket block
#define NEB ((N_EDGES + EPB - 1) / EPB)  // 196 blocks

typedef float  f32x4  __attribute__((ext_vector_type(4)));
typedef __bf16 bf16x8 __attribute__((ext_vector_type(8)));

static __device__ __forceinline__ unsigned short bfbits(float f)
{
    const __bf16 b = (__bf16)f;           // RNE truncation f32 -> bf16
    return __builtin_bit_cast(unsigned short, b);
}
static __device__ __forceinline__ float bfback(unsigned short u)
{
    return (float)__builtin_bit_cast(__bf16, u);
}

// ---------------------------------------------------------------------------
// Phase 0 (R21: compact || wsplit fused into one grid -- independent work,
// one launch). Blocks [0,391) = per-head compaction; [391, 391+512) = Ww
// bf16 hi/lo split.
// ---------------------------------------------------------------------------
#define NCOMPACT ((N_NODES + 255) / 256)          // 391
#define NWSPLIT  ((K * D * D + 255) / 256)        // 512

__global__ __launch_bounds__(256)
void prep_kernel(const float* __restrict__ mask,
                 int* __restrict__ lists,
                 int* __restrict__ cnts,
                 unsigned char* __restrict__ mb,
                 const float* __restrict__ Ww,
                 unsigned short* __restrict__ wtH,
                 unsigned short* __restrict__ wtL)
{
    __shared__ int wcnt[4][K];
    __shared__ int wbase[4][K];

    if (blockIdx.x >= NCOMPACT) {
        // ---- wsplit body ----
        const int t = (blockIdx.x - NCOMPACT) * 256 + threadIdx.x;
        if (t >= K * D * D) return;
        const int k   = t >> 14;       // D*D = 16384
        const int kk  = (t >> 7) & 127;
        const int col = t & 127;
        const float v = Ww[t];
        const __bf16 h = (__bf16)v;
        const __bf16 l = (__bf16)(v - (float)h);
        const int o = (k << 14) | (col << 7) | kk;
        wtH[o] = __builtin_bit_cast(unsigned short, h);
        wtL[o] = __builtin_bit_cast(unsigned short, l);
        return;
    }

    // ---- compact body ----
    const int n = blockIdx.x * 256 + threadIdx.x;
    const int lane = threadIdx.x & 63;
    const int wave = threadIdx.x >> 6;
    const bool valid = (n < N_NODES);

    unsigned long long ball[K];
    int bits8 = 0;
    #pragma unroll
    for (int k = 0; k < K; ++k) {
        const bool m = valid && (mask[(size_t)n * K + k] > 0.0f);
        bits8 |= m ? (1 << k) : 0;
        ball[k] = __ballot(m);
        if (lane == 0) wcnt[wave][k] = __popcll(ball[k]);
    }
    __syncthreads();

    if (threadIdx.x < K) {
        const int k = threadIdx.x;
        const int t0 = wcnt[0][k], t1 = wcnt[1][k], t2 = wcnt[2][k], t3 = wcnt[3][k];
        const int base = (t0 + t1 + t2 + t3)
                       ? atomicAdd(&cnts[k], t0 + t1 + t2 + t3) : 0;
        wbase[0][k] = base;
        wbase[1][k] = base + t0;
        wbase[2][k] = base + t0 + t1;
        wbase[3][k] = base + t0 + t1 + t2;
    }
    __syncthreads();

    #pragma unroll
    for (int k = 0; k < K; ++k) {
        if ((ball[k] >> lane) & 1ull) {
            const int pos = __popcll(ball[k] & ((1ull << lane) - 1ull));
            lists[(size_t)k * N_NODES + wbase[wave][k] + pos] = n;
        }
    }
    if (valid) mb[n] = (unsigned char)bits8;
}

// ---------------------------------------------------------------------------
// Phase 1 (R21: head_gemm || ehist fused). head_gemm is latency-bound with
// spare BW/issue slots (R9/R10: occupancy-insensitive, 800 of 6300 GB/s);
// ehist depends only on ei -- rides along on tail blocks, reusing Ah's LDS
// as the histogram (keeps 52.6KB -> 3 blocks/CU). Removes ehist's serial
// time from the critical path.
// head_gemm body = R9-proven (f32 staging + convert, 94us standalone).
// ---------------------------------------------------------------------------
__global__ __launch_bounds__(512, 4)
void head_gemm_kernel(const float* __restrict__ x,
                      const unsigned short* __restrict__ wtH,
                      const unsigned short* __restrict__ wtL,
                      const float* __restrict__ Wm,
                      const int* __restrict__ lists,
                      const int* __restrict__ cnts,
                      float* __restrict__ t32,
                      float* __restrict__ base32,
                      const int* __restrict__ ei,
                      int* __restrict__ bhist,
                      const int nhg)
{
    __shared__ __align__(16) unsigned short Ah[CHUNK * D];  // 24 KB
    __shared__ __align__(16) unsigned short Al[CHUNK * D];  // 24 KB
    __shared__ float redT[GWAVES][48];                      // 1.5 KB
    __shared__ float redB[CHUNK][4];                        // 1.5 KB
    __shared__ int   ids[CHUNK];                            // 384 B

    const int tid = threadIdx.x;

    if (blockIdx.x >= nhg) {
        // ---- ehist body (512 threads, EPB edges; lh overlays Ah) ----
        int* lh = (int*)Ah;
        for (int i = tid; i < NB; i += 512) lh[i] = 0;
        __syncthreads();
        const int e0 = (blockIdx.x - nhg) * EPB;
        #pragma unroll 4
        for (int i = 0; i < EPB / 512; ++i) {
            const int e = e0 + i * 512 + tid;
            if (e < N_EDGES) atomicAdd(&lh[ei[(long long)N_EDGES + e] >> 7], 1);
        }
        __syncthreads();
        for (int i = tid; i < NB; i += 512) {
            const int c = lh[i];
            if (c) atomicAdd(&bhist[i], c);
        }
        return;
    }

    const int bid = blockIdx.x;
    const int k = (bid >> 3) & 7;
    const int c = ((bid >> 6) << 3) | (bid & 7);   // XCD swizzle

    const int cnt = cnts[k];
    const int nbase = c * CHUNK;
    if (nbase >= cnt) return;            // block-uniform exit (before barriers)

    const int lane = tid & 63;
    const int wave = __builtin_amdgcn_readfirstlane((int)(tid >> 6));
    const int* list = lists + (size_t)k * N_NODES;

    if (tid < CHUNK) {
        int idx = nbase + tid;
        if (idx >= cnt) idx = cnt - 1;   // tail rows duplicated, writes guarded
        ids[tid] = list[idx];
    }
    __syncthreads();

    // ---- stage A (hi/lo bf16, swizzled) + exact fp32 base partials ----
    if (tid < CHUNK * 4) {
        const int r = tid >> 2;          // row 0..95
        const int q = tid & 3;           // 4 threads per row
        const int id = ids[r];
        const float4* xr  = (const float4*)(x + (size_t)id * D);
        const float4* wm4 = (const float4*)(Wm + k * D);
        float bp = 0.0f;
        #pragma unroll
        for (int i = 0; i < 8; ++i) {
            const int f4 = q + 4 * i;    // 4 consecutive lanes = 64B coalesced
            const float4 v  = xr[f4];
            const float4 wv = wm4[f4];
            bp += v.x * wv.x + v.y * wv.y + v.z * wv.z + v.w * wv.w;
            ushort4 h, l;
            h.x = bfbits(v.x); l.x = bfbits(v.x - bfback(h.x));
            h.y = bfbits(v.y); l.y = bfbits(v.y - bfback(h.y));
            h.z = bfbits(v.z); l.z = bfbits(v.z - bfback(h.z));
            h.w = bfbits(v.w); l.w = bfbits(v.w - bfback(h.w));
            const int boff = ((r * 256 + f4 * 8) ^ ((r & 7) << 4)) >> 1;
            *(ushort4*)&Ah[boff] = h;
            *(ushort4*)&Al[boff] = l;
        }
        redB[r][q] = bp;
    }
    __syncthreads();

    // ---- MFMA main loop (no barriers) ----
    const int wm_ = wave >> 2;           // wave_m: rows wm_*48 .. +47
    const int wn  = wave & 3;            // wave_n: cols wn*32 .. +31
    const int l15 = lane & 15;
    const int lg  = lane >> 4;
    const int n0  = wn * 32;

    f32x4 acc[3][2];
    #pragma unroll
    for (int mf = 0; mf < 3; ++mf) {
        acc[mf][0] = (f32x4){0.f, 0.f, 0.f, 0.f};
        acc[mf][1] = (f32x4){0.f, 0.f, 0.f, 0.f};
    }

    const unsigned short* bH0 = wtH + (((k * D + n0 + l15) << 7) + 8 * lg);
    const unsigned short* bH1 = bH0 + (16 << 7);
    const unsigned short* bL0 = wtL + (((k * D + n0 + l15) << 7) + 8 * lg);
    const unsigned short* bL1 = bL0 + (16 << 7);

    #pragma unroll
    for (int s = 0; s < 4; ++s) {
        const int ko = s * 32;
        const bf16x8 Bh0 = *reinterpret_cast<const bf16x8*>(bH0 + ko);
        const bf16x8 Bh1 = *reinterpret_cast<const bf16x8*>(bH1 + ko);
        const bf16x8 Bl0 = *reinterpret_cast<const bf16x8*>(bL0 + ko);
        const bf16x8 Bl1 = *reinterpret_cast<const bf16x8*>(bL1 + ko);
        #pragma unroll
        for (int mf = 0; mf < 3; ++mf) {
            const int m = wm_ * 48 + mf * 16 + l15;
            const int byt = (m * 256 + (ko + 8 * lg) * 2) ^ ((m & 7) << 4);
            const bf16x8 Amh = *reinterpret_cast<const bf16x8*>(&Ah[byt >> 1]);
            const bf16x8 Aml = *reinterpret_cast<const bf16x8*>(&Al[byt >> 1]);
            acc[mf][0] = __builtin_amdgcn_mfma_f32_16x16x32_bf16(Amh, Bh0, acc[mf][0], 0, 0, 0);
            acc[mf][1] = __builtin_amdgcn_mfma_f32_16x16x32_bf16(Amh, Bh1, acc[mf][1], 0, 0, 0);
            acc[mf][0] = __builtin_amdgcn_mfma_f32_16x16x32_bf16(Amh, Bl0, acc[mf][0], 0, 0, 0);
            acc[mf][1] = __builtin_amdgcn_mfma_f32_16x16x32_bf16(Amh, Bl1, acc[mf][1], 0, 0, 0);
            acc[mf][0] = __builtin_amdgcn_mfma_f32_16x16x32_bf16(Aml, Bh0, acc[mf][0], 0, 0, 0);
            acc[mf][1] = __builtin_amdgcn_mfma_f32_16x16x32_bf16(Aml, Bh1, acc[mf][1], 0, 0, 0);
        }
    }

    // ---- epilogue: relu, dot with Wm over this wave's 32 cols, reduce ----
    const float wmv0 = Wm[k * D + n0 + l15];
    const float wmv1 = Wm[k * D + n0 + 16 + l15];
    float keep = 0.0f;
    #pragma unroll
    for (int mf = 0; mf < 3; ++mf) {
        #pragma unroll
        for (int r = 0; r < 4; ++r) {
            float p = fmaxf(acc[mf][0][r], 0.0f) * wmv0
                    + fmaxf(acc[mf][1][r], 0.0f) * wmv1;
            p += __shfl_xor(p, 1);
            p += __shfl_xor(p, 2);
            p += __shfl_xor(p, 4);
            p += __shfl_xor(p, 8);       // all 16 lanes of group lg hold sum
            if (l15 == mf * 4 + r) keep = p;
        }
    }
    if (l15 < 12)
        redT[wave][((l15 >> 2) << 4) + (lg << 2) + (l15 & 3)] = keep;
    __syncthreads();

    if (tid < CHUNK) {
        const int r = tid;
        const int idx = nbase + r;
        if (idx < cnt) {
            const int wg = r / 48;       // wave_m group of this row
            const int rl = r - wg * 48;
            const float ts = redT[wg * 4 + 0][rl] + redT[wg * 4 + 1][rl]
                           + redT[wg * 4 + 2][rl] + redT[wg * 4 + 3][rl];
            const float bs = redB[r][0] + redB[r][1] + redB[r][2] + redB[r][3];
            const int id = ids[r];
            t32[(size_t)id * K + k]    = ts;
            base32[(size_t)id * K + k] = bs;
        }
    }
}

// ---------------------------------------------------------------------------
// Phase 2 (bucketed scatter + fused combine/flag/worklist). R9-proven.
// ---------------------------------------------------------------------------
__global__ __launch_bounds__(1024)
void escan_kernel(const int* __restrict__ bhist,
                  int* __restrict__ bases,
                  int* __restrict__ cursors)
{
    __shared__ int sc[1024];
    const int tid = threadIdx.x;
    const int v = (tid < NB) ? bhist[tid] : 0;
    sc[tid] = v;
    __syncthreads();
    for (int off = 1; off < 1024; off <<= 1) {
        int t = 0;
        if (tid >= off) t = sc[tid - off];
        __syncthreads();
        sc[tid] += t;
        __syncthreads();
    }
    if (tid < NB) {
        const int ex = sc[tid] - v;     // exclusive
        bases[tid]   = ex;
        cursors[tid] = ex;
        if (tid == NB - 1) bases[NB] = sc[tid];
    }
}

__global__ __launch_bounds__(512)
void ebucket_kernel(const int* __restrict__ ei,
                    int* __restrict__ cursors,
                    int* __restrict__ bkt)
{
    __shared__ int lh[NB];
    __shared__ int wb[NB];
    const int tid = threadIdx.x;
    for (int i = tid; i < NB; i += 512) lh[i] = 0;
    __syncthreads();
    const int e0 = blockIdx.x * EPB;
    // pass 1: local counts
    #pragma unroll 4
    for (int i = 0; i < EPB / 512; ++i) {
        const int e = e0 + i * 512 + tid;
        if (e < N_EDGES) atomicAdd(&lh[ei[(long long)N_EDGES + e] >> 7], 1);
    }
    __syncthreads();
    for (int i = tid; i < NB; i += 512) {
        const int c = lh[i];
        wb[i] = c ? atomicAdd(&cursors[i], c) : 0;
        lh[i] = 0;
    }
    __syncthreads();
    // pass 2: rank + write packed records (runs are contiguous -> L2 absorbs)
    #pragma unroll 4
    for (int i = 0; i < EPB / 512; ++i) {
        const int e = e0 + i * 512 + tid;
        if (e < N_EDGES) {
            const int d = ei[(long long)N_EDGES + e];
            const int s = ei[e];
            const int b = d >> 7;
            const int r = atomicAdd(&lh[b], 1);
            const int idx = wb[b] + r;
            if (idx < N_EDGES)           // defensive clamp (always true)
                bkt[idx] = (s << 7) | (d & 127);
        }
    }
}

__global__ __launch_bounds__(512)
void eaccum_kernel(const int* __restrict__ bkt,
                   const int* __restrict__ bases,
                   const unsigned char* __restrict__ mb,
                   const float* __restrict__ t32,
                   const float* __restrict__ base32,
                   float* __restrict__ agg32,
                   float* __restrict__ out,
                   unsigned char* __restrict__ flag8,
                   double* __restrict__ s64,
                   int2* __restrict__ wl,
                   int* __restrict__ wlcnt)
{
    __shared__ float acc[BKT * K];          // 4 KB
    __shared__ unsigned char mbl[BKT];
    __shared__ unsigned char fll[BKT];
    __shared__ int anyfl;
    const int b = blockIdx.x;
    const int n0 = b << 7;
    const int tid = threadIdx.x;
    for (int i = tid; i < BKT * K; i += 512) acc[i] = 0.0f;
    if (tid < BKT) {
        const int n = n0 + tid;
        mbl[tid] = (n < N_NODES) ? mb[n] : 0;
    }
    if (tid == 0) anyfl = 0;
    __syncthreads();

    // ---- accumulate (gate = dst mask only; t32 zero-defined elsewhere) ----
    const int eB = bases[b];
    int eE = bases[b + 1];
    if (eE > N_EDGES) eE = N_EDGES;      // defensive clamp (always no-op)
    for (int e = eB + tid; e < eE; e += 512) {
        const int rec = bkt[e];
        const int s  = rec >> 7;
        const int dl = rec & 127;
        const unsigned md = mbl[dl];
        if (md) {
            const float4* tr = (const float4*)(t32 + (size_t)s * K);
            const float4 t0 = tr[0], t1 = tr[1];
            #pragma unroll
            for (int k = 0; k < K; ++k) {
                const float tv = (k < 4)
                    ? ((k < 2) ? (k == 0 ? t0.x : t0.y) : (k == 2 ? t0.z : t0.w))
                    : ((k < 6) ? (k == 4 ? t1.x : t1.y) : (k == 6 ? t1.z : t1.w));
                if (((md >> k) & 1) && tv != 0.0f)
                    atomicAdd(&acc[(dl << 3) + k], tv);   // ds_add_f32
            }
        }
    }
    __syncthreads();

    // ---- combine + flag for this block's 128 nodes ----
    if (tid < BKT) {
        const int n = n0 + tid;
        if (n < N_NODES) {
            const unsigned m8 = mbl[tid];
            const float4* b4 = (const float4*)(base32 + (size_t)n * K);
            const float4 b40 = b4[0], b41 = b4[1];
            float bs[K];
            bs[0] = b40.x; bs[1] = b40.y; bs[2] = b40.z; bs[3] = b40.w;
            bs[4] = b41.x; bs[5] = b41.y; bs[6] = b41.z; bs[7] = b41.w;
            float o[K];
            int cnt = 0, fl = 0;
            #pragma unroll
            for (int k = 0; k < K; ++k) {
                const float sc = bs[k] + acc[(tid << 3) + k];
                const bool masked = (m8 >> k) & 1;
                const bool hm = masked && (sc > 0.0f);
                if (masked && fabsf(sc) < TAU) fl |= (1 << k);
                o[k] = (hm && cnt < 2) ? 1.0f : 0.0f;
                cnt += hm ? 1 : 0;
            }
            float4* op = (float4*)(out + (size_t)n * K);
            op[0] = make_float4(o[0], o[1], o[2], o[3]);
            op[1] = make_float4(o[4], o[5], o[6], o[7]);
            float4* ap = (float4*)(agg32 + (size_t)n * K);
            ap[0] = make_float4(acc[(tid << 3) + 0], acc[(tid << 3) + 1],
                                acc[(tid << 3) + 2], acc[(tid << 3) + 3]);
            ap[1] = make_float4(acc[(tid << 3) + 4], acc[(tid << 3) + 5],
                                acc[(tid << 3) + 6], acc[(tid << 3) + 7]);
            flag8[n] = (unsigned char)fl;
            fll[tid] = (unsigned char)fl;
            if (fl) {
                anyfl = 1;               // benign race, all write 1
                #pragma unroll
                for (int k = 0; k < K; ++k)
                    if ((fl >> k) & 1) s64[(size_t)n * K + k] = 0.0;
            }
        } else {
            fll[tid] = 0;
        }
    }
    __syncthreads();

    // ---- worklist: rescan OWN records (L2-hot), LDS flag check ----
    if (anyfl) {
        for (int e = eB + tid; e < eE; e += 512) {
            const int rec = bkt[e];
            const int dl = rec & 127;
            unsigned f = fll[dl];
            if (!f) continue;
            const int s = rec >> 7;
            f &= mb[s];                  // rare path: src mask gather ok
            while (f) {
                const int k = __ffs(f) - 1;
                f &= f - 1;
                const int idx = atomicAdd(wlcnt, 1);
                if (idx < WL_CAP) wl[idx] = make_int2(s | (k << 20), n0 + dl);
            }
        }
    }
}

// ---------------------------------------------------------------------------
// Fallback path kernels (used only if ws_size too small for bkt array).
// ---------------------------------------------------------------------------
__global__ __launch_bounds__(256)
void scatter_fallback_kernel(const int* __restrict__ ei,
                             const unsigned char* __restrict__ mb,
                             const float* __restrict__ t32,
                             float* __restrict__ agg32)
{
    const long long tid = (long long)blockIdx.x * 256 + threadIdx.x;
    if (tid >= (long long)N_EDGES * K) return;
    const int k = (int)(tid & (K - 1));
    const long long e = tid >> 3;
    const int d = ei[(long long)N_EDGES + e];
    const int s = ei[e];
    const unsigned md = mb[d] & mb[s];
    if (!((md >> k) & 1)) return;
    const float v = t32[(size_t)s * K + k];
    if (v != 0.0f) atomicAdd(&agg32[(size_t)d * K + k], v);
}

__global__ __launch_bounds__(256)
void combine_flag_kernel(const unsigned char* __restrict__ mb,
                         const float* __restrict__ base32,
                         const float* __restrict__ agg32,
                         float* __restrict__ out,
                         unsigned char* __restrict__ flag8,
                         double* __restrict__ s64)
{
    const int n = blockIdx.x * 256 + threadIdx.x;
    if (n >= N_NODES) return;
    const unsigned m8 = mb[n];
    float o[K];
    int cnt = 0, fl = 0;
    #pragma unroll
    for (int k = 0; k < K; ++k) {
        const float s = base32[(size_t)n * K + k] + agg32[(size_t)n * K + k];
        const bool masked = (m8 >> k) & 1;
        const bool hm = masked && (s > 0.0f);
        if (masked && fabsf(s) < TAU) fl |= (1 << k);
        o[k] = (hm && cnt < 2) ? 1.0f : 0.0f;
        cnt += hm ? 1 : 0;
    }
    float4* op = (float4*)(out + (size_t)n * K);
    op[0] = make_float4(o[0], o[1], o[2], o[3]);
    op[1] = make_float4(o[4], o[5], o[6], o[7]);
    flag8[n] = (unsigned char)fl;
    if (fl) {
        #pragma unroll
        for (int k = 0; k < K; ++k)
            if ((fl >> k) & 1) s64[(size_t)n * K + k] = 0.0;
    }
}

__global__ __launch_bounds__(256)
void edge_flag_kernel(const int* __restrict__ ei,
                      const unsigned char* __restrict__ mb,
                      const unsigned char* __restrict__ flag8,
                      int2* __restrict__ wl,
                      int* __restrict__ wlcnt)
{
    const int e = blockIdx.x * 256 + threadIdx.x;
    if (e >= N_EDGES) return;
    const int d = ei[(long long)N_EDGES + e];
    unsigned f = flag8[d];
    if (!f) return;
    const int s = ei[e];
    f &= mb[s];
    while (f) {
        const int k = __ffs(f) - 1;
        f &= f - 1;
        const int idx = atomicAdd(wlcnt, 1);
        if (idx < WL_CAP) wl[idx] = make_int2(s | (k << 20), d);
    }
}

// ---------------------------------------------------------------------------
// Repair B: one wave per worklist entry: exact fp64 t, atomic into score64.
// ---------------------------------------------------------------------------
__global__ __launch_bounds__(256)
void repair_t_kernel(const float* __restrict__ x,
                     const float* __restrict__ Ww,
                     const float* __restrict__ Wm,
                     const int2* __restrict__ wl,
                     const int* __restrict__ wlcnt,
                     double* __restrict__ score64)
{
    const int lane = threadIdx.x & 63;
    const int waveId = blockIdx.x * 4 + (threadIdx.x >> 6);
    const int nWaves = gridDim.x * 4;
    int cnt = *wlcnt;
    if (cnt > WL_CAP) cnt = WL_CAP;
    for (int w = waveId; w < cnt; w += nWaves) {
        const int2 ent = wl[w];
        const int s = __builtin_amdgcn_readfirstlane(ent.x & 0xFFFFF);
        const int k = __builtin_amdgcn_readfirstlane(ent.x >> 20);
        const int d = ent.y;
        const float* xr = x + (size_t)s * D;
        const float* Wk = Ww + (size_t)k * D * D;
        double c0 = 0.0, c1 = 0.0;
        for (int j = 0; j < D; ++j) {
            const double xd = (double)xr[j];
            c0 = fma(xd, (double)Wk[j * D + lane], c0);
            c1 = fma(xd, (double)Wk[j * D + lane + 64], c1);
        }
        double ts = fmax(c0, 0.0) * (double)Wm[k * D + lane]
                  + fmax(c1, 0.0) * (double)Wm[k * D + lane + 64];
        #pragma unroll
        for (int off = 32; off > 0; off >>= 1) ts += __shfl_xor(ts, off);
        if (lane == 0) atomicAdd(&score64[(size_t)d * K + k], ts);
    }
}

// ---------------------------------------------------------------------------
// Repair C: rewrite output rows of flagged nodes using exact scores.
// ---------------------------------------------------------------------------
__global__ __launch_bounds__(256)
void repair_combine_kernel(const float* __restrict__ x,
                           const unsigned char* __restrict__ mb,
                           const float* __restrict__ Wm,
                           const float* __restrict__ base32,
                           const float* __restrict__ agg32,
                           const double* __restrict__ score64,
                           const unsigned char* __restrict__ flag8,
                           float* __restrict__ out)
{
    const int n = blockIdx.x * 256 + threadIdx.x;
    if (n >= N_NODES) return;
    const unsigned f = flag8[n];
    if (!f) return;
    const unsigned m8 = mb[n];
    float o[K];
    int cnt = 0;
    #pragma unroll
    for (int k = 0; k < K; ++k) {
        bool hm;
        if ((f >> k) & 1) {
            double b = 0.0;
            for (int j = 0; j < D; ++j)
                b = fma((double)x[(size_t)n * D + j], (double)Wm[k * D + j], b);
            hm = (b + score64[(size_t)n * K + k]) > 0.0;
        } else {
            hm = ((m8 >> k) & 1) &&
                 ((base32[(size_t)n * K + k] + agg32[(size_t)n * K + k]) > 0.0f);
        }
        o[k] = (hm && cnt < 2) ? 1.0f : 0.0f;
        cnt += hm ? 1 : 0;
    }
    float4* op = (float4*)(out + (size_t)n * K);
    op[0] = make_float4(o[0], o[1], o[2], o[3]);
    op[1] = make_float4(o[4], o[5], o[6], o[7]);
}

extern "C" void kernel_launch(void* const* d_in, const int* in_sizes, int n_in,
                              void* d_out, int out_size, void* d_ws, size_t ws_size,
                              hipStream_t stream)
{
    const float* x    = (const float*)d_in[0];
    const int*   ei   = (const int*)d_in[1];   // edge_index [2, E] int32
    const float* mask = (const float*)d_in[2]; // [N, K]
    const float* Ww   = (const float*)d_in[3]; // [K, D, D]
    const float* Wm   = (const float*)d_in[4]; // [K, D, 1]
    float* out = (float*)d_out;                // [N, K] float32

    // workspace layout (identical to R9):
    //   [0, 3.2M)            t32      f32[N*K]   (memset 0; head_gemm fills masked)
    //   [3.2M, 6.4M)         agg32    f32[N*K]
    //   [6.4M, 12.8M)        s64      f64[N*K]  (live only from eaccum on)
    //     overlay [6.4M, 9.6M)    lists  int[K][N]          (dead after head_gemm)
    //     overlay [9.6M, 10.13M)  wtH/wtL bf16[K][D][D] x2  (dead after head_gemm)
    //   [12.8M, +100000)     flag8    u8[N]
    //   [12,900,000, +32)    cnts     int[8]
    //   [12,900,032, +4)     wlcnt    int
    //   [12,900,064, +3128)  bhist    int[NB]
    //   [12,903,200, +3132)  bases    int[NB+1]
    //   [12,906,336, +3128)  cursors  int[NB]
    //   [12,909,504, +2M)    wl       int2[WL_CAP]         (ends 15,006,656)
    //   [15,006,656, +3.2M)  b32      f32[N*K]             (ends 18,206,656)
    //   [18,206,656, +100000) mb      u8[N]                (ends 18,306,656)
    //   [18,306,656, +12.8M) bkt      int[N_EDGES]         (ends 31,106,656)
    char* w = (char*)d_ws;
    float*          t32    = (float*)w;
    float*          agg32  = (float*)(w + 3200000);
    double*         s64    = (double*)(w + 6400000);
    int*            lists  = (int*)(w + 6400000);
    unsigned short* wtH    = (unsigned short*)(w + 9600000);
    unsigned short* wtL    = (unsigned short*)(w + 9600000 + 262144);
    unsigned char*  flag8  = (unsigned char*)(w + 12800000);
    int*            cnts   = (int*)(w + 12900000);
    int*            wlcnt  = (int*)(w + 12900032);
    int*            bhist  = (int*)(w + 12900064);
    int*            bases  = (int*)(w + 12903200);
    int*            cursors= (int*)(w + 12906336);
    int2*           wl     = (int2*)(w + 12909504);
    float*          b32    = (float*)(w + 15006656);
    unsigned char*  mb     = (unsigned char*)(w + 18206656);
    int*            bkt    = (int*)(w + 18306656);
    const size_t WS_BUCKETED = 31106656;
    const bool bucketed = (ws_size >= WS_BUCKETED);

    // zero t32 (defines unmasked entries -> eaccum needs no mb[src] gather)
    hipMemsetAsync(t32, 0, 3200000, stream);
    // zero cnts + wlcnt + bhist (bases/cursors fully written by escan)
    hipMemsetAsync(w + 12900000, 0, 4096, stream);

    // compact || wsplit (fused grid)
    prep_kernel<<<NCOMPACT + NWSPLIT, 256, 0, stream>>>(
        mask, lists, cnts, mb, Ww, wtH, wtL);

    // head_gemm || ehist (fused grid): tail NEB blocks histogram dst buckets
    const int nchunks = (N_NODES + CHUNK - 1) / CHUNK;           // 1042
    const int nc8 = (nchunks + 7) & ~7;                           // 1048
    const int nhg = nc8 * K;
    head_gemm_kernel<<<nhg + NEB, 512, 0, stream>>>(
        x, wtH, wtL, Wm, lists, cnts, t32, b32, ei, bhist, nhg);

    if (bucketed) {
        escan_kernel<<<1, 1024, 0, stream>>>(bhist, bases, cursors);
        ebucket_kernel<<<NEB, 512, 0, stream>>>(ei, cursors, bkt);
        eaccum_kernel<<<NB, 512, 0, stream>>>(bkt, bases, mb, t32, b32,
                                              agg32, out, flag8, s64, wl, wlcnt);
    } else {
        hipMemsetAsync(agg32, 0, 3200000, stream);
        const long long nek = (long long)N_EDGES * K;
        scatter_fallback_kernel<<<(int)((nek + 255) / 256), 256, 0, stream>>>(
            ei, mb, t32, agg32);
        combine_flag_kernel<<<(N_NODES + 255) / 256, 256, 0, stream>>>(
            mb, b32, agg32, out, flag8, s64);
        edge_flag_kernel<<<(N_EDGES + 255) / 256, 256, 0, stream>>>(
            ei, mb, flag8, wl, wlcnt);
    }

    repair_t_kernel<<<512, 256, 0, stream>>>(x, Ww, Wm, wl, wlcnt, s64);

    repair_combine_kernel<<<(N_NODES + 255) / 256, 256, 0, stream>>>(
        x, mb, Wm, b32, agg32, s64, flag8, out);
}

// Round 12
// 344.745 us; speedup vs baseline: 1.1491x; 1.0416x over previous
//
#include <hip/hip_runtime.h>

#define N_NODES 100000
#define N_EDGES 3200000
#define D 128
#define K 8

// |score32| below this => exact fp64 repair. bf16x3 GEMM score sigma ~2e-5,
// so 4e-3 is ~200 sigma. Bucketed-scatter LDS-order sums also covered.
#define TAU 4e-3f
#define WL_CAP 262144  // repair worklist capacity

#define CHUNK 96   // nodes per head_gemm block (52.6KB LDS -> 3 blocks/CU)
#define GWAVES 8   // waves per head_gemm block (512 threads, 2x4 wave tiling)

// ---- bucketed scatter geometry (R9-proven) ----
#define BKT 128                          // dst nodes per bucket
#define NB  ((N_NODES + BKT - 1) / BKT)  // 782 buckets
#define EPB 16384                        // edges per hist/bucket block
#define NEB ((N_EDGES + EPB - 1) / EPB)  // 196 blocks

typedef float  f32x4  __attribute__((ext_vector_type(4)));
typedef __bf16 bf16x8 __attribute__((ext_vector_type(8)));

static __device__ __forceinline__ unsigned short bfbits(float f)
{
    const __bf16 b = (__bf16)f;           // RNE truncation f32 -> bf16
    return __builtin_bit_cast(unsigned short, b);
}
static __device__ __forceinline__ float bfback(unsigned short u)
{
    return (float)__builtin_bit_cast(__bf16, u);
}

// ---------------------------------------------------------------------------
// Phase 0 (R22: compact || wsplit || ehist in one grid -- all independent).
// Blocks [0,NCOMPACT) = compaction; [NCOMPACT,+NWSPLIT) = Ww split;
// [NCOMPACT+NWSPLIT,+NEB) = dst-bucket histogram.
// ---------------------------------------------------------------------------
#define NCOMPACT ((N_NODES + 255) / 256)          // 391
#define NWSPLIT  ((K * D * D + 255) / 256)        // 512

__global__ __launch_bounds__(256)
void prep_kernel(const float* __restrict__ mask,
                 int* __restrict__ lists,
                 int* __restrict__ cnts,
                 unsigned char* __restrict__ mb,
                 const float* __restrict__ Ww,
                 unsigned short* __restrict__ wtH,
                 unsigned short* __restrict__ wtL,
                 const int* __restrict__ ei,
                 int* __restrict__ bhist)
{
    __shared__ int lds[NB + 64];         // hist overlay / compact wcnt+wbase

    if (blockIdx.x >= NCOMPACT + NWSPLIT) {
        // ---- ehist body ----
        int* lh = lds;
        const int tid = threadIdx.x;
        for (int i = tid; i < NB; i += 256) lh[i] = 0;
        __syncthreads();
        const int e0 = (blockIdx.x - NCOMPACT - NWSPLIT) * EPB;
        #pragma unroll 4
        for (int i = 0; i < EPB / 256; ++i) {
            const int e = e0 + i * 256 + tid;
            if (e < N_EDGES) atomicAdd(&lh[ei[(long long)N_EDGES + e] >> 7], 1);
        }
        __syncthreads();
        for (int i = tid; i < NB; i += 256) {
            const int c = lh[i];
            if (c) atomicAdd(&bhist[i], c);
        }
        return;
    }

    if (blockIdx.x >= NCOMPACT) {
        // ---- wsplit body ----
        const int t = (blockIdx.x - NCOMPACT) * 256 + threadIdx.x;
        if (t >= K * D * D) return;
        const int k   = t >> 14;       // D*D = 16384
        const int kk  = (t >> 7) & 127;
        const int col = t & 127;
        const float v = Ww[t];
        const __bf16 h = (__bf16)v;
        const __bf16 l = (__bf16)(v - (float)h);
        const int o = (k << 14) | (col << 7) | kk;
        wtH[o] = __builtin_bit_cast(unsigned short, h);
        wtL[o] = __builtin_bit_cast(unsigned short, l);
        return;
    }

    // ---- compact body ----
    int (*wcnt)[K]  = (int(*)[K])lds;
    int (*wbase)[K] = (int(*)[K])(lds + 32);

    const int n = blockIdx.x * 256 + threadIdx.x;
    const int lane = threadIdx.x & 63;
    const int wave = threadIdx.x >> 6;
    const bool valid = (n < N_NODES);

    unsigned long long ball[K];
    int bits8 = 0;
    #pragma unroll
    for (int k = 0; k < K; ++k) {
        const bool m = valid && (mask[(size_t)n * K + k] > 0.0f);
        bits8 |= m ? (1 << k) : 0;
        ball[k] = __ballot(m);
        if (lane == 0) wcnt[wave][k] = __popcll(ball[k]);
    }
    __syncthreads();

    if (threadIdx.x < K) {
        const int k = threadIdx.x;
        const int t0 = wcnt[0][k], t1 = wcnt[1][k], t2 = wcnt[2][k], t3 = wcnt[3][k];
        const int base = (t0 + t1 + t2 + t3)
                       ? atomicAdd(&cnts[k], t0 + t1 + t2 + t3) : 0;
        wbase[0][k] = base;
        wbase[1][k] = base + t0;
        wbase[2][k] = base + t0 + t1;
        wbase[3][k] = base + t0 + t1 + t2;
    }
    __syncthreads();

    #pragma unroll
    for (int k = 0; k < K; ++k) {
        if ((ball[k] >> lane) & 1ull) {
            const int pos = __popcll(ball[k] & ((1ull << lane) - 1ull));
            lists[(size_t)k * N_NODES + wbase[wave][k] + pos] = n;
        }
    }
    if (valid) mb[n] = (unsigned char)bits8;
}

// ---------------------------------------------------------------------------
// Phase 1 (R22: head_gemm || ebucket fused, ebucket blocks at grid FRONT for
// full-duration overlap -- R11's tail placement only overlapped the drain).
// ebucket depends only on escan's cursors; head_gemm is latency-bound with
// spare BW/issue slots (R9/R10). neb=0 in fallback mode (no bkt buffer).
// ---------------------------------------------------------------------------
__global__ __launch_bounds__(512, 4)
void head_gemm_kernel(const float* __restrict__ x,
                      const unsigned short* __restrict__ wtH,
                      const unsigned short* __restrict__ wtL,
                      const float* __restrict__ Wm,
                      const int* __restrict__ lists,
                      const int* __restrict__ cnts,
                      float* __restrict__ t32,
                      float* __restrict__ base32,
                      const int* __restrict__ ei,
                      int* __restrict__ cursors,
                      int* __restrict__ bkt,
                      const int neb)
{
    __shared__ __align__(16) unsigned short Ah[CHUNK * D];  // 24 KB
    __shared__ __align__(16) unsigned short Al[CHUNK * D];  // 24 KB
    __shared__ float redT[GWAVES][48];                      // 1.5 KB
    __shared__ float redB[CHUNK][4];                        // 1.5 KB
    __shared__ int   ids[CHUNK];                            // 384 B

    const int tid = threadIdx.x;

    if ((int)blockIdx.x < neb) {
        // ---- ebucket body (512 threads; lh/wb overlay Ah) ----
        int* lh = (int*)Ah;
        int* wb = lh + NB;
        for (int i = tid; i < NB; i += 512) lh[i] = 0;
        __syncthreads();
        const int e0 = blockIdx.x * EPB;
        // pass 1: local counts
        #pragma unroll 4
        for (int i = 0; i < EPB / 512; ++i) {
            const int e = e0 + i * 512 + tid;
            if (e < N_EDGES) atomicAdd(&lh[ei[(long long)N_EDGES + e] >> 7], 1);
        }
        __syncthreads();
        for (int i = tid; i < NB; i += 512) {
            const int c = lh[i];
            wb[i] = c ? atomicAdd(&cursors[i], c) : 0;
            lh[i] = 0;
        }
        __syncthreads();
        // pass 2: rank + write packed records
        #pragma unroll 4
        for (int i = 0; i < EPB / 512; ++i) {
            const int e = e0 + i * 512 + tid;
            if (e < N_EDGES) {
                const int d = ei[(long long)N_EDGES + e];
                const int s = ei[e];
                const int b = d >> 7;
                const int r = atomicAdd(&lh[b], 1);
                const int idx = wb[b] + r;
                if (idx < N_EDGES)       // defensive clamp (always true)
                    bkt[idx] = (s << 7) | (d & 127);
            }
        }
        return;
    }

    const int bid = blockIdx.x - neb;
    const int k = (bid >> 3) & 7;
    const int c = ((bid >> 6) << 3) | (bid & 7);   // XCD swizzle

    const int cnt = cnts[k];
    const int nbase = c * CHUNK;
    if (nbase >= cnt) return;            // block-uniform exit (before barriers)

    const int lane = tid & 63;
    const int wave = __builtin_amdgcn_readfirstlane((int)(tid >> 6));
    const int* list = lists + (size_t)k * N_NODES;

    if (tid < CHUNK) {
        int idx = nbase + tid;
        if (idx >= cnt) idx = cnt - 1;   // tail rows duplicated, writes guarded
        ids[tid] = list[idx];
    }
    __syncthreads();

    // ---- stage A (hi/lo bf16, swizzled) + exact fp32 base partials ----
    if (tid < CHUNK * 4) {
        const int r = tid >> 2;          // row 0..95
        const int q = tid & 3;           // 4 threads per row
        const int id = ids[r];
        const float4* xr  = (const float4*)(x + (size_t)id * D);
        const float4* wm4 = (const float4*)(Wm + k * D);
        float bp = 0.0f;
        #pragma unroll
        for (int i = 0; i < 8; ++i) {
            const int f4 = q + 4 * i;    // 4 consecutive lanes = 64B coalesced
            const float4 v  = xr[f4];
            const float4 wv = wm4[f4];
            bp += v.x * wv.x + v.y * wv.y + v.z * wv.z + v.w * wv.w;
            ushort4 h, l;
            h.x = bfbits(v.x); l.x = bfbits(v.x - bfback(h.x));
            h.y = bfbits(v.y); l.y = bfbits(v.y - bfback(h.y));
            h.z = bfbits(v.z); l.z = bfbits(v.z - bfback(h.z));
            h.w = bfbits(v.w); l.w = bfbits(v.w - bfback(h.w));
            const int boff = ((r * 256 + f4 * 8) ^ ((r & 7) << 4)) >> 1;
            *(ushort4*)&Ah[boff] = h;
            *(ushort4*)&Al[boff] = l;
        }
        redB[r][q] = bp;
    }
    __syncthreads();

    // ---- MFMA main loop (no barriers) ----
    const int wm_ = wave >> 2;           // wave_m: rows wm_*48 .. +47
    const int wn  = wave & 3;            // wave_n: cols wn*32 .. +31
    const int l15 = lane & 15;
    const int lg  = lane >> 4;
    const int n0  = wn * 32;

    f32x4 acc[3][2];
    #pragma unroll
    for (int mf = 0; mf < 3; ++mf) {
        acc[mf][0] = (f32x4){0.f, 0.f, 0.f, 0.f};
        acc[mf][1] = (f32x4){0.f, 0.f, 0.f, 0.f};
    }

    const unsigned short* bH0 = wtH + (((k * D + n0 + l15) << 7) + 8 * lg);
    const unsigned short* bH1 = bH0 + (16 << 7);
    const unsigned short* bL0 = wtL + (((k * D + n0 + l15) << 7) + 8 * lg);
    const unsigned short* bL1 = bL0 + (16 << 7);

    #pragma unroll
    for (int s = 0; s < 4; ++s) {
        const int ko = s * 32;
        const bf16x8 Bh0 = *reinterpret_cast<const bf16x8*>(bH0 + ko);
        const bf16x8 Bh1 = *reinterpret_cast<const bf16x8*>(bH1 + ko);
        const bf16x8 Bl0 = *reinterpret_cast<const bf16x8*>(bL0 + ko);
        const bf16x8 Bl1 = *reinterpret_cast<const bf16x8*>(bL1 + ko);
        #pragma unroll
        for (int mf = 0; mf < 3; ++mf) {
            const int m = wm_ * 48 + mf * 16 + l15;
            const int byt = (m * 256 + (ko + 8 * lg) * 2) ^ ((m & 7) << 4);
            const bf16x8 Amh = *reinterpret_cast<const bf16x8*>(&Ah[byt >> 1]);
            const bf16x8 Aml = *reinterpret_cast<const bf16x8*>(&Al[byt >> 1]);
            acc[mf][0] = __builtin_amdgcn_mfma_f32_16x16x32_bf16(Amh, Bh0, acc[mf][0], 0, 0, 0);
            acc[mf][1] = __builtin_amdgcn_mfma_f32_16x16x32_bf16(Amh, Bh1, acc[mf][1], 0, 0, 0);
            acc[mf][0] = __builtin_amdgcn_mfma_f32_16x16x32_bf16(Amh, Bl0, acc[mf][0], 0, 0, 0);
            acc[mf][1] = __builtin_amdgcn_mfma_f32_16x16x32_bf16(Amh, Bl1, acc[mf][1], 0, 0, 0);
            acc[mf][0] = __builtin_amdgcn_mfma_f32_16x16x32_bf16(Aml, Bh0, acc[mf][0], 0, 0, 0);
            acc[mf][1] = __builtin_amdgcn_mfma_f32_16x16x32_bf16(Aml, Bh1, acc[mf][1], 0, 0, 0);
        }
    }

    // ---- epilogue: relu, dot with Wm over this wave's 32 cols, reduce ----
    const float wmv0 = Wm[k * D + n0 + l15];
    const float wmv1 = Wm[k * D + n0 + 16 + l15];
    float keep = 0.0f;
    #pragma unroll
    for (int mf = 0; mf < 3; ++mf) {
        #pragma unroll
        for (int r = 0; r < 4; ++r) {
            float p = fmaxf(acc[mf][0][r], 0.0f) * wmv0
                    + fmaxf(acc[mf][1][r], 0.0f) * wmv1;
            p += __shfl_xor(p, 1);
            p += __shfl_xor(p, 2);
            p += __shfl_xor(p, 4);
            p += __shfl_xor(p, 8);       // all 16 lanes of group lg hold sum
            if (l15 == mf * 4 + r) keep = p;
        }
    }
    if (l15 < 12)
        redT[wave][((l15 >> 2) << 4) + (lg << 2) + (l15 & 3)] = keep;
    __syncthreads();

    if (tid < CHUNK) {
        const int r = tid;
        const int idx = nbase + r;
        if (idx < cnt) {
            const int wg = r / 48;       // wave_m group of this row
            const int rl = r - wg * 48;
            const float ts = redT[wg * 4 + 0][rl] + redT[wg * 4 + 1][rl]
                           + redT[wg * 4 + 2][rl] + redT[wg * 4 + 3][rl];
            const float bs = redB[r][0] + redB[r][1] + redB[r][2] + redB[r][3];
            const int id = ids[r];
            t32[(size_t)id * K + k]    = ts;
            base32[(size_t)id * K + k] = bs;
        }
    }
}

// ---------------------------------------------------------------------------
// Phase 2 remainder. R9-proven bodies.
// ---------------------------------------------------------------------------
__global__ __launch_bounds__(1024)
void escan_kernel(const int* __restrict__ bhist,
                  int* __restrict__ bases,
                  int* __restrict__ cursors)
{
    __shared__ int sc[1024];
    const int tid = threadIdx.x;
    const int v = (tid < NB) ? bhist[tid] : 0;
    sc[tid] = v;
    __syncthreads();
    for (int off = 1; off < 1024; off <<= 1) {
        int t = 0;
        if (tid >= off) t = sc[tid - off];
        __syncthreads();
        sc[tid] += t;
        __syncthreads();
    }
    if (tid < NB) {
        const int ex = sc[tid] - v;     // exclusive
        bases[tid]   = ex;
        cursors[tid] = ex;
        if (tid == NB - 1) bases[NB] = sc[tid];
    }
}

__global__ __launch_bounds__(512)
void eaccum_kernel(const int* __restrict__ bkt,
                   const int* __restrict__ bases,
                   const unsigned char* __restrict__ mb,
                   const float* __restrict__ t32,
                   const float* __restrict__ base32,
                   float* __restrict__ agg32,
                   float* __restrict__ out,
                   unsigned char* __restrict__ flag8,
                   double* __restrict__ s64,
                   int2* __restrict__ wl,
                   int* __restrict__ wlcnt)
{
    __shared__ float acc[BKT * K];          // 4 KB
    __shared__ unsigned char mbl[BKT];
    __shared__ unsigned char fll[BKT];
    __shared__ int anyfl;
    const int b = blockIdx.x;
    const int n0 = b << 7;
    const int tid = threadIdx.x;
    for (int i = tid; i < BKT * K; i += 512) acc[i] = 0.0f;
    if (tid < BKT) {
        const int n = n0 + tid;
        mbl[tid] = (n < N_NODES) ? mb[n] : 0;
    }
    if (tid == 0) anyfl = 0;
    __syncthreads();

    // ---- accumulate (gate = dst mask only; t32 zero-defined elsewhere) ----
    const int eB = bases[b];
    int eE = bases[b + 1];
    if (eE > N_EDGES) eE = N_EDGES;      // defensive clamp (always no-op)
    for (int e = eB + tid; e < eE; e += 512) {
        const int rec = bkt[e];
        const int s  = rec >> 7;
        const int dl = rec & 127;
        const unsigned md = mbl[dl];
        if (md) {
            const float4* tr = (const float4*)(t32 + (size_t)s * K);
            const float4 t0 = tr[0], t1 = tr[1];
            #pragma unroll
            for (int k = 0; k < K; ++k) {
                const float tv = (k < 4)
                    ? ((k < 2) ? (k == 0 ? t0.x : t0.y) : (k == 2 ? t0.z : t0.w))
                    : ((k < 6) ? (k == 4 ? t1.x : t1.y) : (k == 6 ? t1.z : t1.w));
                if (((md >> k) & 1) && tv != 0.0f)
                    atomicAdd(&acc[(dl << 3) + k], tv);   // ds_add_f32
            }
        }
    }
    __syncthreads();

    // ---- combine + flag for this block's 128 nodes ----
    if (tid < BKT) {
        const int n = n0 + tid;
        if (n < N_NODES) {
            const unsigned m8 = mbl[tid];
            const float4* b4 = (const float4*)(base32 + (size_t)n * K);
            const float4 b40 = b4[0], b41 = b4[1];
            float bs[K];
            bs[0] = b40.x; bs[1] = b40.y; bs[2] = b40.z; bs[3] = b40.w;
            bs[4] = b41.x; bs[5] = b41.y; bs[6] = b41.z; bs[7] = b41.w;
            float o[K];
            int cnt = 0, fl = 0;
            #pragma unroll
            for (int k = 0; k < K; ++k) {
                const float sc = bs[k] + acc[(tid << 3) + k];
                const bool masked = (m8 >> k) & 1;
                const bool hm = masked && (sc > 0.0f);
                if (masked && fabsf(sc) < TAU) fl |= (1 << k);
                o[k] = (hm && cnt < 2) ? 1.0f : 0.0f;
                cnt += hm ? 1 : 0;
            }
            float4* op = (float4*)(out + (size_t)n * K);
            op[0] = make_float4(o[0], o[1], o[2], o[3]);
            op[1] = make_float4(o[4], o[5], o[6], o[7]);
            float4* ap = (float4*)(agg32 + (size_t)n * K);
            ap[0] = make_float4(acc[(tid << 3) + 0], acc[(tid << 3) + 1],
                                acc[(tid << 3) + 2], acc[(tid << 3) + 3]);
            ap[1] = make_float4(acc[(tid << 3) + 4], acc[(tid << 3) + 5],
                                acc[(tid << 3) + 6], acc[(tid << 3) + 7]);
            flag8[n] = (unsigned char)fl;
            fll[tid] = (unsigned char)fl;
            if (fl) {
                anyfl = 1;               // benign race, all write 1
                #pragma unroll
                for (int k = 0; k < K; ++k)
                    if ((fl >> k) & 1) s64[(size_t)n * K + k] = 0.0;
            }
        } else {
            fll[tid] = 0;
        }
    }
    __syncthreads();

    // ---- worklist: rescan OWN records (L2-hot), LDS flag check ----
    if (anyfl) {
        for (int e = eB + tid; e < eE; e += 512) {
            const int rec = bkt[e];
            const int dl = rec & 127;
            unsigned f = fll[dl];
            if (!f) continue;
            const int s = rec >> 7;
            f &= mb[s];                  // rare path: src mask gather ok
            while (f) {
                const int k = __ffs(f) - 1;
                f &= f - 1;
                const int idx = atomicAdd(wlcnt, 1);
                if (idx < WL_CAP) wl[idx] = make_int2(s | (k << 20), n0 + dl);
            }
        }
    }
}

// ---------------------------------------------------------------------------
// Fallback path kernels (used only if ws_size too small for bkt array).
// ---------------------------------------------------------------------------
__global__ __launch_bounds__(256)
void scatter_fallback_kernel(const int* __restrict__ ei,
                             const unsigned char* __restrict__ mb,
                             const float* __restrict__ t32,
                             float* __restrict__ agg32)
{
    const long long tid = (long long)blockIdx.x * 256 + threadIdx.x;
    if (tid >= (long long)N_EDGES * K) return;
    const int k = (int)(tid & (K - 1));
    const long long e = tid >> 3;
    const int d = ei[(long long)N_EDGES + e];
    const int s = ei[e];
    const unsigned md = mb[d] & mb[s];
    if (!((md >> k) & 1)) return;
    const float v = t32[(size_t)s * K + k];
    if (v != 0.0f) atomicAdd(&agg32[(size_t)d * K + k], v);
}

__global__ __launch_bounds__(256)
void combine_flag_kernel(const unsigned char* __restrict__ mb,
                         const float* __restrict__ base32,
                         const float* __restrict__ agg32,
                         float* __restrict__ out,
                         unsigned char* __restrict__ flag8,
                         double* __restrict__ s64)
{
    const int n = blockIdx.x * 256 + threadIdx.x;
    if (n >= N_NODES) return;
    const unsigned m8 = mb[n];
    float o[K];
    int cnt = 0, fl = 0;
    #pragma unroll
    for (int k = 0; k < K; ++k) {
        const float s = base32[(size_t)n * K + k] + agg32[(size_t)n * K + k];
        const bool masked = (m8 >> k) & 1;
        const bool hm = masked && (s > 0.0f);
        if (masked && fabsf(s) < TAU) fl |= (1 << k);
        o[k] = (hm && cnt < 2) ? 1.0f : 0.0f;
        cnt += hm ? 1 : 0;
    }
    float4* op = (float4*)(out + (size_t)n * K);
    op[0] = make_float4(o[0], o[1], o[2], o[3]);
    op[1] = make_float4(o[4], o[5], o[6], o[7]);
    flag8[n] = (unsigned char)fl;
    if (fl) {
        #pragma unroll
        for (int k = 0; k < K; ++k)
            if ((fl >> k) & 1) s64[(size_t)n * K + k] = 0.0;
    }
}

__global__ __launch_bounds__(256)
void edge_flag_kernel(const int* __restrict__ ei,
                      const unsigned char* __restrict__ mb,
                      const unsigned char* __restrict__ flag8,
                      int2* __restrict__ wl,
                      int* __restrict__ wlcnt)
{
    const int e = blockIdx.x * 256 + threadIdx.x;
    if (e >= N_EDGES) return;
    const int d = ei[(long long)N_EDGES + e];
    unsigned f = flag8[d];
    if (!f) return;
    const int s = ei[e];
    f &= mb[s];
    while (f) {
        const int k = __ffs(f) - 1;
        f &= f - 1;
        const int idx = atomicAdd(wlcnt, 1);
        if (idx < WL_CAP) wl[idx] = make_int2(s | (k << 20), d);
    }
}

// ---------------------------------------------------------------------------
// Repair B: one wave per worklist entry: exact fp64 t, atomic into score64.
// ---------------------------------------------------------------------------
__global__ __launch_bounds__(256)
void repair_t_kernel(const float* __restrict__ x,
                     const float* __restrict__ Ww,
                     const float* __restrict__ Wm,
                     const int2* __restrict__ wl,
                     const int* __restrict__ wlcnt,
                     double* __restrict__ score64)
{
    const int lane = threadIdx.x & 63;
    const int waveId = blockIdx.x * 4 + (threadIdx.x >> 6);
    const int nWaves = gridDim.x * 4;
    int cnt = *wlcnt;
    if (cnt > WL_CAP) cnt = WL_CAP;
    for (int w = waveId; w < cnt; w += nWaves) {
        const int2 ent = wl[w];
        const int s = __builtin_amdgcn_readfirstlane(ent.x & 0xFFFFF);
        const int k = __builtin_amdgcn_readfirstlane(ent.x >> 20);
        const int d = ent.y;
        const float* xr = x + (size_t)s * D;
        const float* Wk = Ww + (size_t)k * D * D;
        double c0 = 0.0, c1 = 0.0;
        for (int j = 0; j < D; ++j) {
            const double xd = (double)xr[j];
            c0 = fma(xd, (double)Wk[j * D + lane], c0);
            c1 = fma(xd, (double)Wk[j * D + lane + 64], c1);
        }
        double ts = fmax(c0, 0.0) * (double)Wm[k * D + lane]
                  + fmax(c1, 0.0) * (double)Wm[k * D + lane + 64];
        #pragma unroll
        for (int off = 32; off > 0; off >>= 1) ts += __shfl_xor(ts, off);
        if (lane == 0) atomicAdd(&score64[(size_t)d * K + k], ts);
    }
}

// ---------------------------------------------------------------------------
// Repair C: rewrite output rows of flagged nodes using exact scores.
// ---------------------------------------------------------------------------
__global__ __launch_bounds__(256)
void repair_combine_kernel(const float* __restrict__ x,
                           const unsigned char* __restrict__ mb,
                           const float* __restrict__ Wm,
                           const float* __restrict__ base32,
                           const float* __restrict__ agg32,
                           const double* __restrict__ score64,
                           const unsigned char* __restrict__ flag8,
                           float* __restrict__ out)
{
    const int n = blockIdx.x * 256 + threadIdx.x;
    if (n >= N_NODES) return;
    const unsigned f = flag8[n];
    if (!f) return;
    const unsigned m8 = mb[n];
    float o[K];
    int cnt = 0;
    #pragma unroll
    for (int k = 0; k < K; ++k) {
        bool hm;
        if ((f >> k) & 1) {
            double b = 0.0;
            for (int j = 0; j < D; ++j)
                b = fma((double)x[(size_t)n * D + j], (double)Wm[k * D + j], b);
            hm = (b + score64[(size_t)n * K + k]) > 0.0;
        } else {
            hm = ((m8 >> k) & 1) &&
                 ((base32[(size_t)n * K + k] + agg32[(size_t)n * K + k]) > 0.0f);
        }
        o[k] = (hm && cnt < 2) ? 1.0f : 0.0f;
        cnt += hm ? 1 : 0;
    }
    float4* op = (float4*)(out + (size_t)n * K);
    op[0] = make_float4(o[0], o[1], o[2], o[3]);
    op[1] = make_float4(o[4], o[5], o[6], o[7]);
}

extern "C" void kernel_launch(void* const* d_in, const int* in_sizes, int n_in,
                              void* d_out, int out_size, void* d_ws, size_t ws_size,
                              hipStream_t stream)
{
    const float* x    = (const float*)d_in[0];
    const int*   ei   = (const int*)d_in[1];   // edge_index [2, E] int32
    const float* mask = (const float*)d_in[2]; // [N, K]
    const float* Ww   = (const float*)d_in[3]; // [K, D, D]
    const float* Wm   = (const float*)d_in[4]; // [K, D, 1]
    float* out = (float*)d_out;                // [N, K] float32

    // workspace layout (identical to R9/R11):
    //   [0, 3.2M)            t32      f32[N*K]   (memset 0; head_gemm fills masked)
    //   [3.2M, 6.4M)         agg32    f32[N*K]
    //   [6.4M, 12.8M)        s64      f64[N*K]  (live only from eaccum on)
    //     overlay [6.4M, 9.6M)    lists  int[K][N]          (dead after head_gemm)
    //     overlay [9.6M, 10.13M)  wtH/wtL bf16[K][D][D] x2  (dead after head_gemm)
    //   [12.8M, +100000)     flag8    u8[N]
    //   [12,900,000, +32)    cnts     int[8]
    //   [12,900,032, +4)     wlcnt    int
    //   [12,900,064, +3128)  bhist    int[NB]
    //   [12,903,200, +3132)  bases    int[NB+1]
    //   [12,906,336, +3128)  cursors  int[NB]
    //   [12,909,504, +2M)    wl       int2[WL_CAP]         (ends 15,006,656)
    //   [15,006,656, +3.2M)  b32      f32[N*K]             (ends 18,206,656)
    //   [18,206,656, +100000) mb      u8[N]                (ends 18,306,656)
    //   [18,306,656, +12.8M) bkt      int[N_EDGES]         (ends 31,106,656)
    char* w = (char*)d_ws;
    float*          t32    = (float*)w;
    float*          agg32  = (float*)(w + 3200000);
    double*         s64    = (double*)(w + 6400000);
    int*            lists  = (int*)(w + 6400000);
    unsigned short* wtH    = (unsigned short*)(w + 9600000);
    unsigned short* wtL    = (unsigned short*)(w + 9600000 + 262144);
    unsigned char*  flag8  = (unsigned char*)(w + 12800000);
    int*            cnts   = (int*)(w + 12900000);
    int*            wlcnt  = (int*)(w + 12900032);
    int*            bhist  = (int*)(w + 12900064);
    int*            bases  = (int*)(w + 12903200);
    int*            cursors= (int*)(w + 12906336);
    int2*           wl     = (int2*)(w + 12909504);
    float*          b32    = (float*)(w + 15006656);
    unsigned char*  mb     = (unsigned char*)(w + 18206656);
    int*            bkt    = (int*)(w + 18306656);
    const size_t WS_BUCKETED = 31106656;
    const bool bucketed = (ws_size >= WS_BUCKETED);

    // zero t32 (defines unmasked entries -> eaccum needs no mb[src] gather)
    hipMemsetAsync(t32, 0, 3200000, stream);
    // zero cnts + wlcnt + bhist (bases/cursors fully written by escan)
    hipMemsetAsync(w + 12900000, 0, 4096, stream);

    // compact || wsplit || ehist (one grid)
    prep_kernel<<<NCOMPACT + NWSPLIT + NEB, 256, 0, stream>>>(
        mask, lists, cnts, mb, Ww, wtH, wtL, ei, bhist);

    // exclusive scan of bucket counts -> bases + cursors
    escan_kernel<<<1, 1024, 0, stream>>>(bhist, bases, cursors);

    // head_gemm || ebucket (ebucket blocks at grid FRONT; neb=0 in fallback)
    const int nchunks = (N_NODES + CHUNK - 1) / CHUNK;           // 1042
    const int nc8 = (nchunks + 7) & ~7;                           // 1048
    const int nhg = nc8 * K;
    const int neb = bucketed ? NEB : 0;
    head_gemm_kernel<<<neb + nhg, 512, 0, stream>>>(
        x, wtH, wtL, Wm, lists, cnts, t32, b32, ei, cursors, bkt, neb);

    if (bucketed) {
        eaccum_kernel<<<NB, 512, 0, stream>>>(bkt, bases, mb, t32, b32,
                                              agg32, out, flag8, s64, wl, wlcnt);
    } else {
        hipMemsetAsync(agg32, 0, 3200000, stream);
        const long long nek = (long long)N_EDGES * K;
        scatter_fallback_kernel<<<(int)((nek + 255) / 256), 256, 0, stream>>>(
            ei, mb, t32, agg32);
        combine_flag_kernel<<<(N_NODES + 255) / 256, 256, 0, stream>>>(
            mb, b32, agg32, out, flag8, s64);
        edge_flag_kernel<<<(N_EDGES + 255) / 256, 256, 0, stream>>>(
            ei, mb, flag8, wl, wlcnt);
    }

    repair_t_kernel<<<512, 256, 0, stream>>>(x, Ww, Wm, wl, wlcnt, s64);

    repair_combine_kernel<<<(N_NODES + 255) / 256, 256, 0, stream>>>(
        x, mb, Wm, b32, agg32, s64, flag8, out);
}